// Round 1
// baseline (1722.834 us; speedup 1.0000x reference)
//
#include <hip/hip_runtime.h>
#include <hip/hip_bf16.h>

#define BB 4
#define TT 1024
#define EE 1024
#define NH 16
#define NKV 4
#define HD 64
#define CM 64   // COPE_MAX_LEN
#define KVDIM (NKV*HD)  // 256

// ---------------- fp32 tiled GEMM:  C[m][n] = sum_k A[m][k]*W[n][k] + bias[n]
// A: [M][K] row-major, W: [N][K] row-major (i.e. computing A @ W^T)
__global__ __launch_bounds__(256) void gemm_f32(const float* __restrict__ A,
                                                const float* __restrict__ W,
                                                const float* __restrict__ bias,
                                                float* __restrict__ C,
                                                int M, int N, int K)
{
    __shared__ float As[16][65];  // [k][m]
    __shared__ float Ws[16][65];  // [k][n]
    const int bm = blockIdx.y * 64;
    const int bn = blockIdx.x * 64;
    const int tid = threadIdx.x;
    const int tx = tid & 15;   // -> n
    const int ty = tid >> 4;   // -> m
    float acc[4][4] = {};
    for (int k0 = 0; k0 < K; k0 += 16) {
        #pragma unroll
        for (int i = 0; i < 4; ++i) {
            int idx = tid + i * 256;
            int r = idx >> 4, c = idx & 15;
            As[c][r] = A[(size_t)(bm + r) * K + k0 + c];
        }
        #pragma unroll
        for (int i = 0; i < 4; ++i) {
            int idx = tid + i * 256;
            int r = idx >> 4, c = idx & 15;
            Ws[c][r] = W[(size_t)(bn + r) * K + k0 + c];
        }
        __syncthreads();
        #pragma unroll
        for (int kk = 0; kk < 16; ++kk) {
            float a[4], b[4];
            #pragma unroll
            for (int i = 0; i < 4; ++i) a[i] = As[kk][ty * 4 + i];
            #pragma unroll
            for (int j = 0; j < 4; ++j) b[j] = Ws[kk][tx * 4 + j];
            #pragma unroll
            for (int i = 0; i < 4; ++i)
                #pragma unroll
                for (int j = 0; j < 4; ++j)
                    acc[i][j] += a[i] * b[j];
        }
        __syncthreads();
    }
    #pragma unroll
    for (int i = 0; i < 4; ++i) {
        int m = bm + ty * 4 + i;
        #pragma unroll
        for (int j = 0; j < 4; ++j) {
            int n = bn + tx * 4 + j;
            C[(size_t)m * N + n] = acc[i][j] + bias[n];
        }
    }
}

// ---------------- fused CoPE attention
// One block = one (b, head, 8-row tile of queries). 256 threads = 4 waves.
#define IB 8
__global__ __launch_bounds__(256) void attn_cope(const float* __restrict__ Q,
                                                 const float* __restrict__ K,
                                                 const float* __restrict__ V,
                                                 const float* __restrict__ pos_emb,
                                                 float* __restrict__ AO)
{
    __shared__ float qs[IB][HD];        // 2 KB
    __shared__ float sims[IB][TT];      // 32 KB
    __shared__ float ks[64][HD + 1];    // 16.6 KB
    __shared__ float li[IB][CM];        // 2 KB

    const int blk  = blockIdx.x;                 // ((b*NH + head) * (T/IB) + ib)
    const int ib   = blk % (TT / IB);
    const int bh   = blk / (TT / IB);
    const int head = bh % NH;
    const int b    = bh / NH;
    const int kv   = head % NKV;
    const int i0   = ib * IB;

    const int tid  = threadIdx.x;
    const int lane = tid & 63;
    const int wave = tid >> 6;

    // ---- load q rows into LDS
    for (int idx = tid; idx < IB * HD; idx += 256) {
        int r = idx >> 6, d = idx & 63;
        qs[r][d] = Q[(size_t)(b * TT + i0 + r) * EE + head * HD + d];
    }
    __syncthreads();

    // ---- phase 2: sims[i][j] = q_i . k_j / 8
    const int i4 = wave;      // wave -> base row
    const int jl = lane;
    for (int jt = 0; jt < TT / 64; ++jt) {
        for (int idx = tid; idx < 64 * HD; idx += 256) {
            int jj = idx >> 6, d = idx & 63;
            ks[jj][d] = K[(size_t)(b * TT + jt * 64 + jj) * KVDIM + kv * HD + d];
        }
        __syncthreads();
        #pragma unroll
        for (int ii = 0; ii < IB / 4; ++ii) {
            int i = i4 + ii * 4;
            float acc = 0.f;
            #pragma unroll
            for (int d = 0; d < HD; ++d) acc += qs[i][d] * ks[jl][d];
            sims[i][jt * 64 + jl] = acc * 0.125f;
        }
        __syncthreads();
    }

    // ---- phase 3: per-row (wave-per-row): CoPE bias + softmax
    const int RPW = IB / 4;   // rows per wave = 2
    for (int rr = 0; rr < RPW; ++rr) {
        int i = wave * RPW + rr;
        // 3a: li[i][m] = q_i . pos_emb[:, m]   (lane = m)
        {
            float acc = 0.f;
            #pragma unroll
            for (int d = 0; d < HD; ++d) acc += qs[i][d] * pos_emb[d * CM + lane];
            li[i][lane] = acc;
        }
        // 3b: gates -> suffix-sum positions -> interp bias -> softmax
        float exf[TT / 64];   // exclusive prefix of gates at this j
        float carry = 0.f;
        #pragma unroll
        for (int c = 0; c < TT / 64; ++c) {
            float s = sims[i][c * 64 + lane];
            float gate = 1.f / (1.f + expf(-s));
            float inc = gate;
            #pragma unroll
            for (int off = 1; off < 64; off <<= 1) {
                float n = __shfl_up(inc, off, 64);
                if (lane >= off) inc += n;
            }
            exf[c] = carry + (inc - gate);
            carry += __shfl(inc, 63, 64);
        }
        const float total = carry;
        float aw[TT / 64];
        float rmax = -1e30f;
        #pragma unroll
        for (int c = 0; c < TT / 64; ++c) {
            float s = sims[i][c * 64 + lane];
            float pos = total - exf[c];
            pos = fminf(fmaxf(pos, 0.f), (float)(CM - 1));
            float pf = floorf(pos);
            float w  = pos - pf;
            int lo = (int)pf;
            int hi = lo + (w > 0.f ? 1 : 0);
            float bias = li[i][hi] * w + li[i][lo] * (1.f - w);
            float a = s + bias;
            aw[c] = a;
            rmax = fmaxf(rmax, a);
        }
        #pragma unroll
        for (int off = 32; off; off >>= 1) rmax = fmaxf(rmax, __shfl_xor(rmax, off, 64));
        float rsum = 0.f;
        #pragma unroll
        for (int c = 0; c < TT / 64; ++c) { aw[c] = expf(aw[c] - rmax); rsum += aw[c]; }
        #pragma unroll
        for (int off = 32; off; off >>= 1) rsum += __shfl_xor(rsum, off, 64);
        const float inv = 1.f / rsum;
        #pragma unroll
        for (int c = 0; c < TT / 64; ++c) sims[i][c * 64 + lane] = aw[c] * inv;
    }

    // ---- phase 4: out[i][d] = sum_j p[j] * v[j][d]    (lane = d)
    for (int rr = 0; rr < RPW; ++rr) {
        int i = wave * RPW + rr;
        float acc = 0.f;
        const float* vp = V + (size_t)(b * TT) * KVDIM + kv * HD + lane;
        #pragma unroll 8
        for (int j = 0; j < TT; ++j) {
            acc += sims[i][j] * vp[(size_t)j * KVDIM];
        }
        AO[(size_t)(b * TT + i0 + i) * EE + head * HD + lane] = acc;
    }
}

extern "C" void kernel_launch(void* const* d_in, const int* in_sizes, int n_in,
                              void* d_out, int out_size, void* d_ws, size_t ws_size,
                              hipStream_t stream)
{
    const float* query   = (const float*)d_in[0];
    const float* key     = (const float*)d_in[1];
    const float* value   = (const float*)d_in[2];
    const float* wq      = (const float*)d_in[3];
    const float* bq      = (const float*)d_in[4];
    const float* wk      = (const float*)d_in[5];
    const float* bk      = (const float*)d_in[6];
    const float* wv      = (const float*)d_in[7];
    const float* bv      = (const float*)d_in[8];
    const float* wo      = (const float*)d_in[9];
    const float* bo      = (const float*)d_in[10];
    const float* pos_emb = (const float*)d_in[11];
    float* out = (float*)d_out;

    float* Qb = (float*)d_ws;                         // 4096*1024
    float* Kb = Qb + (size_t)BB * TT * EE;            // 4096*256
    float* Vb = Kb + (size_t)BB * TT * KVDIM;         // 4096*256
    float* AO = Vb + (size_t)BB * TT * KVDIM;         // 4096*1024

    const int M = BB * TT;  // 4096

    // Q/K/V projections
    gemm_f32<<<dim3(EE / 64, M / 64), 256, 0, stream>>>(query, wq, bq, Qb, M, EE, EE);
    gemm_f32<<<dim3(KVDIM / 64, M / 64), 256, 0, stream>>>(key, wk, bk, Kb, M, KVDIM, EE);
    gemm_f32<<<dim3(KVDIM / 64, M / 64), 256, 0, stream>>>(value, wv, bv, Vb, M, KVDIM, EE);

    // fused CoPE attention
    attn_cope<<<BB * NH * (TT / IB), 256, 0, stream>>>(Qb, Kb, Vb, pos_emb, AO);

    // output projection
    gemm_f32<<<dim3(EE / 64, M / 64), 256, 0, stream>>>(AO, wo, bo, out, M, EE, EE);
}

// Round 2
// 543.997 us; speedup vs baseline: 3.1670x; 3.1670x over previous
//
#include <hip/hip_runtime.h>
#include <hip/hip_bf16.h>
#include <stdint.h>

typedef unsigned short u16;
typedef __attribute__((ext_vector_type(8))) short short8;
typedef __attribute__((ext_vector_type(4))) float f32x4;

#define BB 4
#define TT 1024
#define EE 1024
#define NH 16
#define NKV 4
#define HD 64
#define SS 1036   // sims row stride (f32) — uniform LDS slot spread for b128 reads

__device__ inline u16 f2bf(float f) {
    uint32_t u = __float_as_uint(f);
    uint32_t r = u + 0x7fffu + ((u >> 16) & 1u);
    return (u16)(r >> 16);
}

__device__ inline f32x4 mfma16(short8 a, short8 b, f32x4 c) {
    return __builtin_amdgcn_mfma_f32_16x16x32_bf16(a, b, c, 0, 0, 0);
}

// Swizzled LDS tile [rows][64] bf16 (row stride 128 B). byte ^= (row&7)<<4
// makes both staged writes and column-fragment b128 reads bank-uniform.
__device__ inline void tile_write8(u16* lds, int row, int c8, short8 v) {
    *(short8*)((char*)lds + ((row * 128 + c8 * 16) ^ ((row & 7) << 4))) = v;
}
__device__ inline short8 tile_read8(const u16* lds, int row, int kbyte) {
    return *(const short8*)((const char*)lds + ((row * 128 + kbyte) ^ ((row & 7) << 4)));
}

// ---------------- bf16 MFMA GEMM: C[m][n] = sum_k A[m][k]*W[n][k] + bias[n]
// A: f32 or bf16 [M][K]; W: f32 [N][K]. Tile 64(M)x128(N), BK=64, 4 waves.
__global__ __launch_bounds__(256) void gemm_mfma(const void* __restrict__ Aptr, int a_bf16,
                                                 const float* __restrict__ W,
                                                 const float* __restrict__ bias,
                                                 float* __restrict__ Cf, u16* __restrict__ Ch,
                                                 int vtrans, int M, int N, int K)
{
    __shared__ u16 As[64 * 64];
    __shared__ u16 Bs[128 * 64];
    const int bm = blockIdx.y * 64, bn = blockIdx.x * 128;
    const int t = threadIdx.x, l = t & 63;
    const int w = t >> 6, wr = w >> 1, wc = w & 1;
    const int lc = l & 15, lg = l >> 4;

    f32x4 acc[2][4];
    #pragma unroll
    for (int i = 0; i < 2; ++i)
        #pragma unroll
        for (int j = 0; j < 4; ++j) acc[i][j] = (f32x4){0.f, 0.f, 0.f, 0.f};

    for (int k0 = 0; k0 < K; k0 += 64) {
        #pragma unroll
        for (int r = 0; r < 2; ++r) {
            int idx = t + r * 256, row = idx >> 3, c8 = idx & 7;
            size_t off = (size_t)(bm + row) * K + k0 + c8 * 8;
            short8 v;
            if (a_bf16) {
                v = *(const short8*)((const u16*)Aptr + off);
            } else {
                const f32x4* p = (const f32x4*)((const float*)Aptr + off);
                f32x4 x = p[0], y = p[1];
                v = (short8){(short)f2bf(x[0]), (short)f2bf(x[1]), (short)f2bf(x[2]), (short)f2bf(x[3]),
                             (short)f2bf(y[0]), (short)f2bf(y[1]), (short)f2bf(y[2]), (short)f2bf(y[3])};
            }
            tile_write8(As, row, c8, v);
        }
        #pragma unroll
        for (int r = 0; r < 4; ++r) {
            int idx = t + r * 256, row = idx >> 3, c8 = idx & 7;
            const f32x4* p = (const f32x4*)(W + (size_t)(bn + row) * K + k0 + c8 * 8);
            f32x4 x = p[0], y = p[1];
            short8 v = (short8){(short)f2bf(x[0]), (short)f2bf(x[1]), (short)f2bf(x[2]), (short)f2bf(x[3]),
                                (short)f2bf(y[0]), (short)f2bf(y[1]), (short)f2bf(y[2]), (short)f2bf(y[3])};
            tile_write8(Bs, row, c8, v);
        }
        __syncthreads();
        #pragma unroll
        for (int ks = 0; ks < 2; ++ks) {
            short8 af[2], bfv[4];
            #pragma unroll
            for (int fi = 0; fi < 2; ++fi)
                af[fi] = tile_read8(As, wr * 32 + fi * 16 + lc, (ks * 32 + lg * 8) * 2);
            #pragma unroll
            for (int fj = 0; fj < 4; ++fj)
                bfv[fj] = tile_read8(Bs, wc * 64 + fj * 16 + lc, (ks * 32 + lg * 8) * 2);
            #pragma unroll
            for (int fi = 0; fi < 2; ++fi)
                #pragma unroll
                for (int fj = 0; fj < 4; ++fj)
                    acc[fi][fj] = mfma16(af[fi], bfv[fj], acc[fi][fj]);
        }
        __syncthreads();
    }
    // epilogue: D row=(lg*4+r) from A, col=lc from B
    #pragma unroll
    for (int fj = 0; fj < 4; ++fj) {
        int col = bn + wc * 64 + fj * 16 + lc;
        float bv = bias[col];
        #pragma unroll
        for (int fi = 0; fi < 2; ++fi) {
            #pragma unroll
            for (int r = 0; r < 4; ++r) {
                int row = bm + wr * 32 + fi * 16 + lg * 4 + r;
                float v = acc[fi][fj][r] + bv;
                if (Cf) Cf[(size_t)row * N + col] = v;
                if (Ch) {
                    if (!vtrans) {
                        Ch[(size_t)row * N + col] = f2bf(v);
                    } else {  // V: write per-head transposed: [(b,kv,d)][t]
                        int bb = row >> 10, tt = row & 1023, kv = col >> 6, d = col & 63;
                        Ch[(size_t)((bb * NKV + kv) * HD + d) * 1024 + tt] = f2bf(v);
                    }
                }
            }
        }
    }
}

// ---------------- pos_emb [d][m] f32 -> PT [m][d] bf16
__global__ __launch_bounds__(256) void cast_posT(const float* __restrict__ pe, u16* __restrict__ PT) {
    int t = blockIdx.x * 256 + threadIdx.x;  // 0..4095
    PT[t] = f2bf(pe[(t & 63) * 64 + (t >> 6)]);
}

// ---------------- fused CoPE attention, MFMA. Block = (b, head, 16 q-rows).
__global__ __launch_bounds__(256) void attn_mfma(const u16* __restrict__ Qh,
                                                 const u16* __restrict__ Kh,
                                                 const u16* __restrict__ VhT,
                                                 const u16* __restrict__ PT,
                                                 u16* __restrict__ AOh)
{
    __shared__ float sims[16 * SS];   // 66,304 B
    __shared__ u16 kvt[64 * 64];      // 8 KB (K tiles, then V tiles)
    __shared__ float li[16 * 64];     // 4 KB

    const int blk = blockIdx.x;
    const int it = blk & 63, bh = blk >> 6;
    const int head = bh & 15, b = bh >> 4, kvh = head & 3;
    const int i0 = it * 16;
    const int t = threadIdx.x, l = t & 63, w = t >> 6;
    const int lc = l & 15, lg = l >> 4;

    // Q A-fragments (rows i0..i0+15, k=d 0..63) — same for all waves
    short8 qf[2];
    #pragma unroll
    for (int kk = 0; kk < 2; ++kk)
        qf[kk] = *(const short8*)(Qh + (size_t)(b * TT + i0 + lc) * EE + head * HD + kk * 32 + lg * 8);

    // li[i][m] = q_i . pos_emb[:,m]  (wave w -> m-subtile w; B from global PT)
    {
        f32x4 a = {0.f, 0.f, 0.f, 0.f};
        #pragma unroll
        for (int kk = 0; kk < 2; ++kk) {
            short8 bfr = *(const short8*)(PT + (w * 16 + lc) * 64 + kk * 32 + lg * 8);
            a = mfma16(qf[kk], bfr, a);
        }
        #pragma unroll
        for (int r = 0; r < 4; ++r) li[(lg * 4 + r) * 64 + w * 16 + lc] = a[r];
    }

    // ---- QK^T: sims[i][j] = q_i.k_j / 8
    const u16* kbase = Kh + (size_t)(b * TT) * (NKV * HD) + kvh * HD;
    for (int jt = 0; jt < 16; ++jt) {
        #pragma unroll
        for (int r = 0; r < 2; ++r) {
            int idx = t + r * 256, row = idx >> 3, c8 = idx & 7;
            short8 v = *(const short8*)(kbase + (size_t)(jt * 64 + row) * (NKV * HD) + c8 * 8);
            tile_write8(kvt, row, c8, v);
        }
        __syncthreads();
        f32x4 a = {0.f, 0.f, 0.f, 0.f};
        #pragma unroll
        for (int kk = 0; kk < 2; ++kk)
            a = mfma16(qf[kk], tile_read8(kvt, w * 16 + lc, (kk * 32 + lg * 8) * 2), a);
        #pragma unroll
        for (int r = 0; r < 4; ++r)
            sims[(lg * 4 + r) * SS + jt * 64 + w * 16 + lc] = a[r] * 0.125f;
        __syncthreads();
    }

    // ---- CoPE bias + softmax (wave-parallel per row, 4 rows/wave)
    #pragma unroll 1
    for (int rr = 0; rr < 4; ++rr) {
        const int i = w * 4 + rr;
        float exf[16];
        float carry = 0.f;
        #pragma unroll
        for (int c = 0; c < 16; ++c) {
            float s = sims[i * SS + c * 64 + l];
            float gate = 1.f / (1.f + __expf(-s));
            float inc = gate;
            #pragma unroll
            for (int off = 1; off < 64; off <<= 1) {
                float n = __shfl_up(inc, off, 64);
                if (l >= off) inc += n;
            }
            exf[c] = carry + (inc - gate);
            carry += __shfl(inc, 63, 64);
        }
        const float total = carry;
        float aw[16];
        float rmax = -1e30f;
        #pragma unroll
        for (int c = 0; c < 16; ++c) {
            float s = sims[i * SS + c * 64 + l];
            float pos = total - exf[c];
            pos = fminf(fmaxf(pos, 0.f), 63.f);
            float pf = floorf(pos);
            float wt = pos - pf;
            int lo = (int)pf;
            int hi = lo + (wt > 0.f ? 1 : 0);
            float bias = li[i * 64 + hi] * wt + li[i * 64 + lo] * (1.f - wt);
            float a = s + bias;
            aw[c] = a;
            rmax = fmaxf(rmax, a);
        }
        #pragma unroll
        for (int off = 32; off; off >>= 1) rmax = fmaxf(rmax, __shfl_xor(rmax, off, 64));
        float rsum = 0.f;
        #pragma unroll
        for (int c = 0; c < 16; ++c) { aw[c] = __expf(aw[c] - rmax); rsum += aw[c]; }
        #pragma unroll
        for (int off = 32; off; off >>= 1) rsum += __shfl_xor(rsum, off, 64);
        const float inv = 1.f / rsum;
        #pragma unroll
        for (int c = 0; c < 16; ++c) sims[i * SS + c * 64 + l] = aw[c] * inv;
    }
    __syncthreads();

    // ---- PV: out[i][d] = sum_j P[i][j] * V[j][d]  (wave w -> d-subtile w)
    const u16* vbase = VhT + (size_t)((b * NKV + kvh) * HD) * 1024;
    f32x4 oacc = {0.f, 0.f, 0.f, 0.f};
    for (int jt = 0; jt < 16; ++jt) {
        #pragma unroll
        for (int r = 0; r < 2; ++r) {
            int idx = t + r * 256, row = idx >> 3, c8 = idx & 7;  // row = d
            short8 v = *(const short8*)(vbase + (size_t)row * 1024 + jt * 64 + c8 * 8);
            tile_write8(kvt, row, c8, v);
        }
        __syncthreads();
        #pragma unroll
        for (int kt = 0; kt < 2; ++kt) {
            const f32x4* pp = (const f32x4*)&sims[lc * SS + jt * 64 + kt * 32 + lg * 8];
            f32x4 x = pp[0], y = pp[1];
            short8 pa = (short8){(short)f2bf(x[0]), (short)f2bf(x[1]), (short)f2bf(x[2]), (short)f2bf(x[3]),
                                 (short)f2bf(y[0]), (short)f2bf(y[1]), (short)f2bf(y[2]), (short)f2bf(y[3])};
            oacc = mfma16(pa, tile_read8(kvt, w * 16 + lc, (kt * 32 + lg * 8) * 2), oacc);
        }
        __syncthreads();
    }
    #pragma unroll
    for (int r = 0; r < 4; ++r)
        AOh[(size_t)(b * TT + i0 + lg * 4 + r) * EE + head * HD + w * 16 + lc] = f2bf(oacc[r]);
}

extern "C" void kernel_launch(void* const* d_in, const int* in_sizes, int n_in,
                              void* d_out, int out_size, void* d_ws, size_t ws_size,
                              hipStream_t stream)
{
    const float* query   = (const float*)d_in[0];
    const float* key     = (const float*)d_in[1];
    const float* value   = (const float*)d_in[2];
    const float* wq      = (const float*)d_in[3];
    const float* bq      = (const float*)d_in[4];
    const float* wk      = (const float*)d_in[5];
    const float* bk      = (const float*)d_in[6];
    const float* wv      = (const float*)d_in[7];
    const float* bv      = (const float*)d_in[8];
    const float* wo      = (const float*)d_in[9];
    const float* bo      = (const float*)d_in[10];
    const float* pos_emb = (const float*)d_in[11];
    float* out = (float*)d_out;

    char* wsb = (char*)d_ws;
    u16* Qh  = (u16*)(wsb);                          // 8 MB  [token][1024]
    u16* Kh  = (u16*)(wsb + ((size_t)8 << 20));      // 2 MB  [token][256]
    u16* VhT = (u16*)(wsb + ((size_t)10 << 20));     // 2 MB  [(b,kv,d)][t]
    u16* AOh = (u16*)(wsb + ((size_t)12 << 20));     // 8 MB  [token][1024]
    u16* PT  = (u16*)(wsb + ((size_t)20 << 20));     // 8 KB  [m][d]

    const int M = BB * TT;  // 4096

    cast_posT<<<16, 256, 0, stream>>>(pos_emb, PT);

    gemm_mfma<<<dim3(EE / 128, M / 64), 256, 0, stream>>>(query, 0, wq, bq, nullptr, Qh, 0, M, EE, EE);
    gemm_mfma<<<dim3((NKV * HD) / 128, M / 64), 256, 0, stream>>>(key, 0, wk, bk, nullptr, Kh, 0, M, NKV * HD, EE);
    gemm_mfma<<<dim3((NKV * HD) / 128, M / 64), 256, 0, stream>>>(value, 0, wv, bv, nullptr, VhT, 1, M, NKV * HD, EE);

    attn_mfma<<<BB * NH * (TT / 16), 256, 0, stream>>>(Qh, Kh, VhT, PT, AOh);

    gemm_mfma<<<dim3(EE / 128, M / 64), 256, 0, stream>>>(AOh, 1, wo, bo, out, nullptr, 0, M, EE, EE);
}

// Round 3
// 387.049 us; speedup vs baseline: 4.4512x; 1.4055x over previous
//
#include <hip/hip_runtime.h>
#include <hip/hip_bf16.h>
#include <stdint.h>

typedef unsigned short u16;
typedef __attribute__((ext_vector_type(8))) short short8;
typedef __attribute__((ext_vector_type(4))) float f32x4;

#define BB 4
#define TT 1024
#define EE 1024
#define NH 16
#define NKV 4
#define HD 64
#define KVD 256
#define SR 1028   // sims row stride in floats (4112 B: 16B-aligned, bank-phase spread)

__device__ inline u16 f2bf(float f) {
    uint32_t u = __float_as_uint(f);
    uint32_t r = u + 0x7fffu + ((u >> 16) & 1u);
    return (u16)(r >> 16);
}

__device__ inline f32x4 mfma16(short8 a, short8 b, f32x4 c) {
    return __builtin_amdgcn_mfma_f32_16x16x32_bf16(a, b, c, 0, 0, 0);
}

// sims layout: self-inverse XOR of float-index bits 2-4 by col bits 5-7.
// Keeps 4-float groups contiguous & aligned; balances banks for all phases.
__device__ inline int simsIdx(int row, int col) {
    return row * SR + (col ^ (((col >> 5) & 7) << 2));
}

// Swizzled bf16 LDS tile [rows][64] (row stride 128 B). byte ^= (row&7)<<4.
__device__ inline void tile_write8(u16* lds, int row, int c8, short8 v) {
    *(short8*)((char*)lds + ((row * 128 + c8 * 16) ^ ((row & 7) << 4))) = v;
}
__device__ inline short8 tile_read8(const u16* lds, int row, int kbyte) {
    return *(const short8*)((const char*)lds + ((row * 128 + kbyte) ^ ((row & 7) << 4)));
}

__device__ inline void gload16(const u16* g, u16* l) {
    __builtin_amdgcn_global_load_lds((const __attribute__((address_space(1))) void*)g,
                                     (__attribute__((address_space(3))) void*)l, 16, 0, 0);
}

// ---------------- f32 -> bf16 cast, 8 elements/thread (n multiple of 2048)
__global__ __launch_bounds__(256) void cast_bf16(const float* __restrict__ s,
                                                 u16* __restrict__ d) {
    int i = blockIdx.x * 256 + threadIdx.x;
    const f32x4* p = (const f32x4*)(s + (size_t)i * 8);
    f32x4 x = p[0], y = p[1];
    short8 v = (short8){(short)f2bf(x[0]), (short)f2bf(x[1]), (short)f2bf(x[2]), (short)f2bf(x[3]),
                        (short)f2bf(y[0]), (short)f2bf(y[1]), (short)f2bf(y[2]), (short)f2bf(y[3])};
    *(short8*)(d + (size_t)i * 8) = v;
}

// ---------------- pos_emb [d][m] f32 -> PT [m][d] bf16
__global__ __launch_bounds__(256) void cast_posT(const float* __restrict__ pe, u16* __restrict__ PT) {
    int t = blockIdx.x * 256 + threadIdx.x;  // 0..4095
    PT[t] = f2bf(pe[(t & 63) * 64 + (t >> 6)]);
}

// ---------------- bf16 MFMA GEMM: C[m][n] = sum_k A[m][k]*W[n][k] + bias[n]
// Tile 64(M) x 128(N), BK=64, 4 waves. W pre-cast bf16, staged via
// global_load_lds (linear dest + inverse-swizzled source); A reg-staged.
__global__ __launch_bounds__(256) void gemm_big(const void* __restrict__ Aptr, int a_bf16,
                                                const u16* __restrict__ Wh,
                                                const float* __restrict__ bias,
                                                float* __restrict__ Cf, u16* __restrict__ Ch,
                                                int vtrans, int M, int N, int K)
{
    __shared__ u16 As[64 * 64];    // swizzled
    __shared__ u16 Bs[128 * 64];   // linear (gload_lds), read with XOR
    const int bm = blockIdx.y * 64, bn = blockIdx.x * 128;
    const int t = threadIdx.x, l = t & 63, w = t >> 6;
    const int wr = w >> 1, wc = w & 1, lc = l & 15, lg = l >> 4;
    const int c8s = (l & 7) ^ ((l >> 3) & 7);   // pre-swizzled source col8

    f32x4 acc[2][4];
    #pragma unroll
    for (int i = 0; i < 2; ++i)
        #pragma unroll
        for (int j = 0; j < 4; ++j) acc[i][j] = (f32x4){0.f, 0.f, 0.f, 0.f};

    for (int k0 = 0; k0 < K; k0 += 64) {
        // W panel: 16 x 1KB chunks, 4 gload per wave. Lane l fills chunk+l*16B.
        #pragma unroll
        for (int r = 0; r < 4; ++r) {
            int chunk = w * 4 + r;
            int row = chunk * 8 + (l >> 3);
            gload16(&Wh[(size_t)(bn + row) * K + k0 + c8s * 8], &Bs[chunk * 512]);
        }
        // A panel: reg-staged (+f32->bf16), swizzled write
        #pragma unroll
        for (int r = 0; r < 2; ++r) {
            int idx = t + r * 256, row = idx >> 3, c8 = idx & 7;
            short8 v;
            if (a_bf16) {
                v = *(const short8*)((const u16*)Aptr + (size_t)(bm + row) * K + k0 + c8 * 8);
            } else {
                const f32x4* p = (const f32x4*)((const float*)Aptr + (size_t)(bm + row) * K + k0 + c8 * 8);
                f32x4 x = p[0], y = p[1];
                v = (short8){(short)f2bf(x[0]), (short)f2bf(x[1]), (short)f2bf(x[2]), (short)f2bf(x[3]),
                             (short)f2bf(y[0]), (short)f2bf(y[1]), (short)f2bf(y[2]), (short)f2bf(y[3])};
            }
            tile_write8(As, row, c8, v);
        }
        __syncthreads();
        #pragma unroll
        for (int ks = 0; ks < 2; ++ks) {
            short8 af[2], bfv[4];
            #pragma unroll
            for (int fi = 0; fi < 2; ++fi)
                af[fi] = tile_read8(As, wr * 32 + fi * 16 + lc, (ks * 32 + lg * 8) * 2);
            #pragma unroll
            for (int fj = 0; fj < 4; ++fj) {
                int row = wc * 64 + fj * 16 + lc;
                bfv[fj] = *(const short8*)((const char*)Bs +
                            ((row * 128 + (ks * 32 + lg * 8) * 2) ^ ((row & 7) << 4)));
            }
            #pragma unroll
            for (int fi = 0; fi < 2; ++fi)
                #pragma unroll
                for (int fj = 0; fj < 4; ++fj)
                    acc[fi][fj] = mfma16(af[fi], bfv[fj], acc[fi][fj]);
        }
        __syncthreads();
    }
    #pragma unroll
    for (int fj = 0; fj < 4; ++fj) {
        int col = bn + wc * 64 + fj * 16 + lc;
        float bv = bias[col];
        #pragma unroll
        for (int fi = 0; fi < 2; ++fi) {
            #pragma unroll
            for (int r = 0; r < 4; ++r) {
                int row = bm + wr * 32 + fi * 16 + lg * 4 + r;
                float v = acc[fi][fj][r] + bv;
                if (Cf) Cf[(size_t)row * N + col] = v;
                if (Ch) {
                    if (!vtrans) {
                        Ch[(size_t)row * N + col] = f2bf(v);
                    } else {  // V: write per-head transposed: [(b,kv,d)][t]
                        int bb = row >> 10, tt = row & 1023, kv = col >> 6, d = col & 63;
                        Ch[(size_t)((bb * NKV + kv) * HD + d) * 1024 + tt] = f2bf(v);
                    }
                }
            }
        }
    }
}

// ---------------- fused CoPE attention. Block = (b, head, 16 q-rows), 4 waves.
// K/V B-fragments straight from global (L2-resident). 2 barriers total.
__global__ __launch_bounds__(256) void attn_mfma(const u16* __restrict__ Qh,
                                                 const u16* __restrict__ Kh,
                                                 const u16* __restrict__ VhT,
                                                 const u16* __restrict__ PT,
                                                 u16* __restrict__ AOh)
{
    __shared__ float sims[16 * SR];   // 65,792 B
    __shared__ float li[16 * 65];     // 4,160 B

    const int blk = blockIdx.x;
    const int it = blk & 63, bh = blk >> 6;
    const int head = bh & 15, b = bh >> 4, kvh = head & 3;
    const int i0 = it * 16;
    const int t = threadIdx.x, l = t & 63, w = t >> 6;
    const int lc = l & 15, lg = l >> 4;

    // Q A-fragments (rows i0..i0+15, k=d 0..63)
    short8 qf[2];
    #pragma unroll
    for (int kk = 0; kk < 2; ++kk)
        qf[kk] = *(const short8*)(Qh + (size_t)(b * TT + i0 + lc) * EE + head * HD + kk * 32 + lg * 8);

    // li[i][m] = q_i . pos_emb[:,m]
    {
        f32x4 a = {0.f, 0.f, 0.f, 0.f};
        #pragma unroll
        for (int kk = 0; kk < 2; ++kk) {
            short8 bfr = *(const short8*)(PT + (w * 16 + lc) * 64 + kk * 32 + lg * 8);
            a = mfma16(qf[kk], bfr, a);
        }
        #pragma unroll
        for (int r = 0; r < 4; ++r) li[(lg * 4 + r) * 65 + w * 16 + lc] = a[r];
    }

    // ---- QK^T: wave w covers cols w*16..w*16+15 of each 64-block
    const u16* kb = Kh + (size_t)(b * TT) * KVD + kvh * HD;
    #pragma unroll 2
    for (int jt = 0; jt < 16; ++jt) {
        const int j0 = jt * 64 + w * 16;
        const u16* kr = kb + (size_t)(j0 + lc) * KVD;
        short8 k0v = *(const short8*)(kr + lg * 8);
        short8 k1v = *(const short8*)(kr + 32 + lg * 8);
        f32x4 a = {0.f, 0.f, 0.f, 0.f};
        a = mfma16(qf[0], k0v, a);
        a = mfma16(qf[1], k1v, a);
        #pragma unroll
        for (int r = 0; r < 4; ++r)
            sims[simsIdx(lg * 4 + r, j0 + lc)] = a[r] * 0.125f;
    }
    __syncthreads();

    // ---- CoPE scan + softmax: lane l owns contiguous j = l*16..l*16+15
    #pragma unroll 1
    for (int rr = 0; rr < 4; ++rr) {
        const int i = w * 4 + rr;
        float sv[16];
        #pragma unroll
        for (int q = 0; q < 4; ++q) {
            f32x4 x = *(const f32x4*)&sims[simsIdx(i, l * 16 + q * 4)];
            sv[q * 4 + 0] = x[0]; sv[q * 4 + 1] = x[1];
            sv[q * 4 + 2] = x[2]; sv[q * 4 + 3] = x[3];
        }
        // local exclusive prefix of gates
        float lexcl[16];
        float ex = 0.f;
        #pragma unroll
        for (int k = 0; k < 16; ++k) {
            lexcl[k] = ex;
            ex += __fdividef(1.f, 1.f + __expf(-sv[k]));
        }
        // single cross-lane inclusive scan of lane totals
        float v = ex;
        #pragma unroll
        for (int off = 1; off < 64; off <<= 1) {
            float n = __shfl_up(v, off, 64);
            if (l >= off) v += n;
        }
        const float total = __shfl(v, 63, 64);
        const float lexb = v - ex;   // exclusive-over-lanes base
        float rmax = -1e30f;
        #pragma unroll
        for (int k = 0; k < 16; ++k) {
            float pos = total - (lexb + lexcl[k]);
            pos = fminf(fmaxf(pos, 0.f), 63.f);
            float pf = floorf(pos);
            float wt = pos - pf;
            int lo = (int)pf;
            int hi = lo + (wt > 0.f ? 1 : 0);
            float bias = li[i * 65 + hi] * wt + li[i * 65 + lo] * (1.f - wt);
            sv[k] += bias;
            rmax = fmaxf(rmax, sv[k]);
        }
        #pragma unroll
        for (int off = 32; off; off >>= 1) rmax = fmaxf(rmax, __shfl_xor(rmax, off, 64));
        float rsum = 0.f;
        #pragma unroll
        for (int k = 0; k < 16; ++k) { sv[k] = __expf(sv[k] - rmax); rsum += sv[k]; }
        #pragma unroll
        for (int off = 32; off; off >>= 1) rsum += __shfl_xor(rsum, off, 64);
        const float inv = __fdividef(1.f, rsum);
        #pragma unroll
        for (int q = 0; q < 4; ++q) {
            f32x4 x = {sv[q * 4 + 0] * inv, sv[q * 4 + 1] * inv,
                       sv[q * 4 + 2] * inv, sv[q * 4 + 3] * inv};
            *(f32x4*)&sims[simsIdx(i, l * 16 + q * 4)] = x;
        }
    }
    __syncthreads();

    // ---- PV: wave w -> d-subtile w; V B-frags straight from global VhT
    const u16* vr = VhT + ((size_t)((b * NKV + kvh) * HD) + w * 16 + lc) * TT;
    f32x4 oacc = {0.f, 0.f, 0.f, 0.f};
    #pragma unroll 2
    for (int jt = 0; jt < 16; ++jt) {
        #pragma unroll
        for (int kt = 0; kt < 2; ++kt) {
            int col = jt * 64 + kt * 32 + lg * 8;
            f32x4 x = *(const f32x4*)&sims[simsIdx(lc, col)];
            f32x4 y = *(const f32x4*)&sims[simsIdx(lc, col + 4)];
            short8 pa = (short8){(short)f2bf(x[0]), (short)f2bf(x[1]), (short)f2bf(x[2]), (short)f2bf(x[3]),
                                 (short)f2bf(y[0]), (short)f2bf(y[1]), (short)f2bf(y[2]), (short)f2bf(y[3])};
            short8 vf = *(const short8*)(vr + col);
            oacc = mfma16(pa, vf, oacc);
        }
    }
    #pragma unroll
    for (int r = 0; r < 4; ++r)
        AOh[(size_t)(b * TT + i0 + lg * 4 + r) * EE + head * HD + w * 16 + lc] = f2bf(oacc[r]);
}

extern "C" void kernel_launch(void* const* d_in, const int* in_sizes, int n_in,
                              void* d_out, int out_size, void* d_ws, size_t ws_size,
                              hipStream_t stream)
{
    const float* query   = (const float*)d_in[0];
    const float* key     = (const float*)d_in[1];
    const float* value   = (const float*)d_in[2];
    const float* wq      = (const float*)d_in[3];
    const float* bq      = (const float*)d_in[4];
    const float* wk      = (const float*)d_in[5];
    const float* bk      = (const float*)d_in[6];
    const float* wv      = (const float*)d_in[7];
    const float* bv      = (const float*)d_in[8];
    const float* wo      = (const float*)d_in[9];
    const float* bo      = (const float*)d_in[10];
    const float* pos_emb = (const float*)d_in[11];
    float* out = (float*)d_out;

    char* wsb = (char*)d_ws;
    u16* Qh  = (u16*)(wsb);                          // 8 MB  [token][1024]
    u16* Kh  = (u16*)(wsb + ((size_t)8  << 20));     // 2 MB  [token][256]
    u16* VhT = (u16*)(wsb + ((size_t)10 << 20));     // 2 MB  [(b,kv,d)][t]
    u16* AOh = (u16*)(wsb + ((size_t)12 << 20));     // 8 MB  [token][1024]
    u16* PT  = (u16*)(wsb + ((size_t)20 << 20));     // 8 KB  [m][d]
    u16* wqh = (u16*)(wsb + ((size_t)21 << 20));     // 2 MB
    u16* wkh = (u16*)(wsb + ((size_t)23 << 20));     // 0.5 MB
    u16* wvh = (u16*)(wsb + ((size_t)23 << 20) + ((size_t)512 << 10));  // 0.5 MB
    u16* woh = (u16*)(wsb + ((size_t)24 << 20));     // 2 MB

    const int M = BB * TT;  // 4096

    cast_posT<<<16, 256, 0, stream>>>(pos_emb, PT);
    cast_bf16<<<512, 256, 0, stream>>>(wq, wqh);   // 1M elements
    cast_bf16<<<128, 256, 0, stream>>>(wk, wkh);   // 256K
    cast_bf16<<<128, 256, 0, stream>>>(wv, wvh);
    cast_bf16<<<512, 256, 0, stream>>>(wo, woh);

    gemm_big<<<dim3(EE / 128, M / 64), 256, 0, stream>>>(query, 0, wqh, bq, nullptr, Qh, 0, M, EE, EE);
    gemm_big<<<dim3(KVD / 128, M / 64), 256, 0, stream>>>(key, 0, wkh, bk, nullptr, Kh, 0, M, KVD, EE);
    gemm_big<<<dim3(KVD / 128, M / 64), 256, 0, stream>>>(value, 0, wvh, bv, nullptr, VhT, 1, M, KVD, EE);

    attn_mfma<<<BB * NH * (TT / 16), 256, 0, stream>>>(Qh, Kh, VhT, PT, AOh);

    gemm_big<<<dim3(EE / 128, M / 64), 256, 0, stream>>>(AOh, 1, woh, bo, out, nullptr, 0, M, EE, EE);
}

// Round 5
// 343.873 us; speedup vs baseline: 5.0101x; 1.1256x over previous
//
#include <hip/hip_runtime.h>
#include <hip/hip_bf16.h>
#include <stdint.h>

typedef unsigned short u16;
typedef __attribute__((ext_vector_type(8))) short short8;
typedef __attribute__((ext_vector_type(4))) float f32x4;

#define BB 4
#define TT 1024
#define EE 1024
#define NH 16
#define NKV 4
#define HD 64
#define KVD 256
#define SR 1028   // sims row stride in floats (4112 B -> natural 4-bank/row stagger)

__device__ inline u16 f2bf(float f) {
    uint32_t u = __float_as_uint(f);
    uint32_t r = u + 0x7fffu + ((u >> 16) & 1u);
    return (u16)(r >> 16);
}

__device__ inline f32x4 mfma16(short8 a, short8 b, f32x4 c) {
    return __builtin_amdgcn_mfma_f32_16x16x32_bf16(a, b, c, 0, 0, 0);
}

// f32 sims region: self-inverse XOR of float-index bits 2-4 by col bits 5-7.
__device__ inline int simsIdx(int row, int col) {
    return row * SR + (col ^ (((col >> 5) & 7) << 2));
}

__device__ inline void gload16(const u16* g, u16* l) {
    __builtin_amdgcn_global_load_lds((const __attribute__((address_space(1))) void*)g,
                                     (__attribute__((address_space(3))) void*)l, 16, 0, 0);
}

__device__ inline void cast8(const float* s, u16* d) {
    const f32x4* p = (const f32x4*)s;
    f32x4 x = p[0], y = p[1];
    short8 v = (short8){(short)f2bf(x[0]), (short)f2bf(x[1]), (short)f2bf(x[2]), (short)f2bf(x[3]),
                        (short)f2bf(y[0]), (short)f2bf(y[1]), (short)f2bf(y[2]), (short)f2bf(y[3])};
    *(short8*)d = v;
}

// ---------------- fused f32->bf16 cast of all 7 tensors (counts in 8-elem units)
__global__ __launch_bounds__(256) void cast_all(
    const float* s0, u16* d0, int n0, const float* s1, u16* d1, int n1,
    const float* s2, u16* d2, int n2, const float* s3, u16* d3, int n3,
    const float* s4, u16* d4, int n4, const float* s5, u16* d5, int n5,
    const float* s6, u16* d6, int n6)
{
    int u = blockIdx.x * 256 + threadIdx.x;
    const float* s; u16* d; int off = u;
    if      (off < n0)              { s = s0; d = d0; }
    else if ((off -= n0) < n1)      { s = s1; d = d1; }
    else if ((off -= n1) < n2)      { s = s2; d = d2; }
    else if ((off -= n2) < n3)      { s = s3; d = d3; }
    else if ((off -= n3) < n4)      { s = s4; d = d4; }
    else if ((off -= n4) < n5)      { s = s5; d = d5; }
    else if ((off -= n5) < n6)      { s = s6; d = d6; }
    else return;
    cast8(s + (size_t)off * 8, d + (size_t)off * 8);
}

// ---------------- pos_emb [d][m] f32 -> PT [m][d] bf16
__global__ __launch_bounds__(256) void cast_posT(const float* __restrict__ pe, u16* __restrict__ PT) {
    int t = blockIdx.x * 256 + threadIdx.x;  // 0..4095
    PT[t] = f2bf(pe[(t & 63) * 64 + (t >> 6)]);
}

// ---------------- GEMM core: C += A[bm:,k] * W[bn:,k]^T, both bf16 [rows][K].
// Both panels via global_load_lds (linear LDS dest + inverse-swizzled source col).
template<int BM, int BN>
__device__ inline void gemm_core(const u16* __restrict__ A, const u16* __restrict__ W,
                                 int K, int bm, int bn, u16* As, u16* Bs,
                                 f32x4 (&acc)[BM / 32][BN / 32])
{
    const int t = threadIdx.x, l = t & 63, w = t >> 6;
    const int wr = w >> 1, wc = w & 1, lc = l & 15, lg = l >> 4;
    const int lr8 = l >> 3;
    const int c8s = (l & 7) ^ lr8;          // pre-swizzled source col8
    constexpr int FI = BM / 32, FJ = BN / 32;
    constexpr int NCA = BM / 8, NCW = BN / 8;

    for (int k0 = 0; k0 < K; k0 += 64) {
        #pragma unroll
        for (int r = 0; r < NCA / 4; ++r) {
            int chunk = w * (NCA / 4) + r;
            gload16(&A[(size_t)(bm + chunk * 8 + lr8) * K + k0 + c8s * 8], &As[chunk * 512]);
        }
        #pragma unroll
        for (int r = 0; r < NCW / 4; ++r) {
            int chunk = w * (NCW / 4) + r;
            gload16(&W[(size_t)(bn + chunk * 8 + lr8) * K + k0 + c8s * 8], &Bs[chunk * 512]);
        }
        __syncthreads();
        #pragma unroll
        for (int ks = 0; ks < 2; ++ks) {
            short8 af[FI], bfr[FJ];
            #pragma unroll
            for (int fi = 0; fi < FI; ++fi) {
                int row = wr * (BM / 2) + fi * 16 + lc;
                af[fi] = *(const short8*)((const char*)As +
                           ((row * 128 + (ks * 32 + lg * 8) * 2) ^ ((row & 7) << 4)));
            }
            #pragma unroll
            for (int fj = 0; fj < FJ; ++fj) {
                int row = wc * (BN / 2) + fj * 16 + lc;
                bfr[fj] = *(const short8*)((const char*)Bs +
                            ((row * 128 + (ks * 32 + lg * 8) * 2) ^ ((row & 7) << 4)));
            }
            #pragma unroll
            for (int fi = 0; fi < FI; ++fi)
                #pragma unroll
                for (int fj = 0; fj < FJ; ++fj)
                    acc[fi][fj] = mfma16(af[fi], bfr[fj], acc[fi][fj]);
        }
        __syncthreads();
    }
}

// ---------------- generic GEMM: writes f32 (Cf) or bf16 (Ch)
template<int BM, int BN>
__global__ __launch_bounds__(256) void gemm_bf16(const u16* __restrict__ A,
                                                 const u16* __restrict__ W,
                                                 const float* __restrict__ bias,
                                                 float* __restrict__ Cf, u16* __restrict__ Ch,
                                                 int M, int N, int K)
{
    __shared__ u16 As[BM * 64], Bs[BN * 64];
    const int bm = blockIdx.y * BM, bn = blockIdx.x * BN;
    const int l = threadIdx.x & 63, w = threadIdx.x >> 6;
    const int wr = w >> 1, wc = w & 1, lc = l & 15, lg = l >> 4;
    constexpr int FI = BM / 32, FJ = BN / 32;

    f32x4 acc[FI][FJ];
    #pragma unroll
    for (int i = 0; i < FI; ++i)
        #pragma unroll
        for (int j = 0; j < FJ; ++j) acc[i][j] = (f32x4){0.f, 0.f, 0.f, 0.f};

    gemm_core<BM, BN>(A, W, K, bm, bn, As, Bs, acc);

    #pragma unroll
    for (int fj = 0; fj < FJ; ++fj) {
        int col = bn + wc * (BN / 2) + fj * 16 + lc;
        float bv = bias[col];
        #pragma unroll
        for (int fi = 0; fi < FI; ++fi)
            #pragma unroll
            for (int r = 0; r < 4; ++r) {
                int row = bm + wr * (BM / 2) + fi * 16 + lg * 4 + r;
                float v = acc[fi][fj][r] + bv;
                if (Cf) Cf[(size_t)row * N + col] = v;
                else    Ch[(size_t)row * N + col] = f2bf(v);
            }
    }
}

// ---------------- fused K+V projection (BM=BN=64). blockIdx.y<64 -> K, else V.
__global__ __launch_bounds__(256) void kv_gemm(const u16* __restrict__ Ki, const u16* __restrict__ Vi,
                                               const u16* __restrict__ Wk, const u16* __restrict__ Wv,
                                               const float* __restrict__ bk, const float* __restrict__ bv,
                                               u16* __restrict__ Kh, u16* __restrict__ VhT)
{
    __shared__ u16 As[64 * 64], Bs[64 * 64];
    const int by = blockIdx.y;
    const bool isV = by >= 64;
    const u16* A = isV ? Vi : Ki;
    const u16* W = isV ? Wv : Wk;
    const float* bias = isV ? bv : bk;
    const int bm = (isV ? by - 64 : by) * 64, bn = blockIdx.x * 64;
    const int l = threadIdx.x & 63, w = threadIdx.x >> 6;
    const int wr = w >> 1, wc = w & 1, lc = l & 15, lg = l >> 4;

    f32x4 acc[2][2];
    #pragma unroll
    for (int i = 0; i < 2; ++i)
        #pragma unroll
        for (int j = 0; j < 2; ++j) acc[i][j] = (f32x4){0.f, 0.f, 0.f, 0.f};

    gemm_core<64, 64>(A, W, EE, bm, bn, As, Bs, acc);

    #pragma unroll
    for (int fj = 0; fj < 2; ++fj) {
        int col = bn + wc * 32 + fj * 16 + lc;
        float bvv = bias[col];
        #pragma unroll
        for (int fi = 0; fi < 2; ++fi)
            #pragma unroll
            for (int r = 0; r < 4; ++r) {
                int row = bm + wr * 32 + fi * 16 + lg * 4 + r;
                float v = acc[fi][fj][r] + bvv;
                if (!isV) {
                    Kh[(size_t)row * KVD + col] = f2bf(v);
                } else {  // V transposed per head: [(b,kv,d)][t]
                    int bb = row >> 10, tt = row & 1023, kv = col >> 6, d = col & 63;
                    VhT[(size_t)((bb * NKV + kv) * HD + d) * TT + tt] = f2bf(v);
                }
            }
    }
}

// ---------------- fused CoPE attention. Block = (b, head, 16 q-rows), 4 waves.
__global__ __launch_bounds__(256) void attn_mfma(const u16* __restrict__ Qh,
                                                 const u16* __restrict__ Kh,
                                                 const u16* __restrict__ VhT,
                                                 const u16* __restrict__ PT,
                                                 u16* __restrict__ AOh)
{
    __shared__ float sims[16 * SR];   // 65,792 B (f32 S; later row-prefix reused as bf16 P)
    __shared__ float li[16 * 65];     // 4,160 B (col 64 = pad 0)
    __shared__ float rinv[16];

    const int blk = blockIdx.x;
    const int it = blk & 63, bh = blk >> 6;
    const int head = bh & 15, b = bh >> 4, kvh = head & 3;
    const int i0 = it * 16;
    const int t = threadIdx.x, l = t & 63, w = t >> 6;
    const int lc = l & 15, lg = l >> 4;

    // Q A-fragments (rows i0..i0+15, k=d 0..63)
    short8 qf[2];
    #pragma unroll
    for (int kk = 0; kk < 2; ++kk)
        qf[kk] = *(const short8*)(Qh + (size_t)(b * TT + i0 + lc) * EE + head * HD + kk * 32 + lg * 8);

    // li[i][m] = q_i . pos_emb[:,m]
    {
        f32x4 a = {0.f, 0.f, 0.f, 0.f};
        #pragma unroll
        for (int kk = 0; kk < 2; ++kk) {
            short8 bfr = *(const short8*)(PT + (w * 16 + lc) * 64 + kk * 32 + lg * 8);
            a = mfma16(qf[kk], bfr, a);
        }
        #pragma unroll
        for (int r = 0; r < 4; ++r) li[(lg * 4 + r) * 65 + w * 16 + lc] = a[r];
    }
    if (t < 16) li[t * 65 + 64] = 0.f;   // pad for lo+1 gather

    // ---- QK^T: wave w covers cols w*16..w*16+15 of each 64-block
    const u16* kb = Kh + (size_t)(b * TT) * KVD + kvh * HD;
    #pragma unroll 2
    for (int jt = 0; jt < 16; ++jt) {
        const int j0 = jt * 64 + w * 16;
        const u16* kr = kb + (size_t)(j0 + lc) * KVD;
        short8 k0v = *(const short8*)(kr + lg * 8);
        short8 k1v = *(const short8*)(kr + 32 + lg * 8);
        f32x4 a = {0.f, 0.f, 0.f, 0.f};
        a = mfma16(qf[0], k0v, a);
        a = mfma16(qf[1], k1v, a);
        #pragma unroll
        for (int r = 0; r < 4; ++r)
            sims[simsIdx(lg * 4 + r, j0 + lc)] = a[r] * 0.125f;
    }
    __syncthreads();

    // ---- CoPE scan + softmax; pack unnormalized P (bf16) in place
    #pragma unroll 1
    for (int rr = 0; rr < 4; ++rr) {
        const int i = w * 4 + rr;
        float sv[16];
        #pragma unroll
        for (int q = 0; q < 4; ++q) {
            f32x4 x = *(const f32x4*)&sims[simsIdx(i, l * 16 + q * 4)];
            sv[q * 4 + 0] = x[0]; sv[q * 4 + 1] = x[1];
            sv[q * 4 + 2] = x[2]; sv[q * 4 + 3] = x[3];
        }
        // local exclusive prefix of gates + single cross-lane scan
        float lexcl[16];
        float ex = 0.f;
        #pragma unroll
        for (int k = 0; k < 16; ++k) {
            lexcl[k] = ex;
            ex += __fdividef(1.f, 1.f + __expf(-sv[k]));
        }
        float v = ex;
        #pragma unroll
        for (int off = 1; off < 64; off <<= 1) {
            float n = __shfl_up(v, off, 64);
            if (l >= off) v += n;
        }
        const float total = __shfl(v, 63, 64);
        const float lexb = v - ex;
        const float* lp = &li[i * 65];
        float rmax = -1e30f;
        #pragma unroll
        for (int k = 0; k < 16; ++k) {
            float pos = total - (lexb + lexcl[k]);
            pos = fminf(fmaxf(pos, 0.f), 63.f);
            float pf = floorf(pos);
            float wt = pos - pf;
            int lo = (int)pf;
            float l0 = lp[lo], l1 = lp[lo + 1];
            sv[k] += l0 + wt * (l1 - l0);
            rmax = fmaxf(rmax, sv[k]);
        }
        #pragma unroll
        for (int off = 32; off; off >>= 1) rmax = fmaxf(rmax, __shfl_xor(rmax, off, 64));
        float rsum = 0.f;
        #pragma unroll
        for (int k = 0; k < 16; ++k) { sv[k] = __expf(sv[k] - rmax); rsum += sv[k]; }
        #pragma unroll
        for (int off = 32; off; off >>= 1) rsum += __shfl_xor(rsum, off, 64);
        if (l == 0) rinv[i] = __fdividef(1.f, rsum);
        // pack unnormalized P into row-prefix (bytes [0,2048) of the row)
        u16* sp = (u16*)sims + (size_t)i * (SR * 2) + l * 16;
        short8 p0 = (short8){(short)f2bf(sv[0]), (short)f2bf(sv[1]), (short)f2bf(sv[2]), (short)f2bf(sv[3]),
                             (short)f2bf(sv[4]), (short)f2bf(sv[5]), (short)f2bf(sv[6]), (short)f2bf(sv[7])};
        short8 p1 = (short8){(short)f2bf(sv[8]), (short)f2bf(sv[9]), (short)f2bf(sv[10]), (short)f2bf(sv[11]),
                             (short)f2bf(sv[12]), (short)f2bf(sv[13]), (short)f2bf(sv[14]), (short)f2bf(sv[15])};
        *(short8*)sp = p0;
        *(short8*)(sp + 8) = p1;
    }
    __syncthreads();

    // ---- PV: wave w -> d-subtile w; P bf16 frags from LDS, V from global
    const u16* sp = (const u16*)sims;
    const u16* vr = VhT + ((size_t)((b * NKV + kvh) * HD) + w * 16 + lc) * TT;
    f32x4 oacc = {0.f, 0.f, 0.f, 0.f};
    #pragma unroll 2
    for (int jt = 0; jt < 16; ++jt) {
        #pragma unroll
        for (int kt = 0; kt < 2; ++kt) {
            int col = jt * 64 + kt * 32 + lg * 8;
            short8 pa = *(const short8*)(sp + (size_t)lc * (SR * 2) + col);
            short8 vf = *(const short8*)(vr + col);
            oacc = mfma16(pa, vf, oacc);
        }
    }
    #pragma unroll
    for (int r = 0; r < 4; ++r) {
        float o = oacc[r] * rinv[lg * 4 + r];
        AOh[(size_t)(b * TT + i0 + lg * 4 + r) * EE + head * HD + w * 16 + lc] = f2bf(o);
    }
}

extern "C" void kernel_launch(void* const* d_in, const int* in_sizes, int n_in,
                              void* d_out, int out_size, void* d_ws, size_t ws_size,
                              hipStream_t stream)
{
    const float* query   = (const float*)d_in[0];
    const float* key     = (const float*)d_in[1];
    const float* value   = (const float*)d_in[2];
    const float* wq      = (const float*)d_in[3];
    const float* bq      = (const float*)d_in[4];
    const float* wk      = (const float*)d_in[5];
    const float* bk      = (const float*)d_in[6];
    const float* wv      = (const float*)d_in[7];
    const float* bv      = (const float*)d_in[8];
    const float* wo      = (const float*)d_in[9];
    const float* bo      = (const float*)d_in[10];
    const float* pos_emb = (const float*)d_in[11];
    float* out = (float*)d_out;

    char* wsb = (char*)d_ws;
    u16* Qh  = (u16*)(wsb);                          // 8 MB  [token][1024]
    u16* Kh  = (u16*)(wsb + ((size_t)8  << 20));     // 2 MB  [token][256]
    u16* VhT = (u16*)(wsb + ((size_t)10 << 20));     // 2 MB  [(b,kv,d)][t]
    u16* Qi  = (u16*)(wsb + ((size_t)12 << 20));     // 8 MB  query bf16 (dead after Q-GEMM)
    u16* AOh = Qi;                                   // 8 MB  attn out (reuses Qi)
    u16* PT  = (u16*)(wsb + ((size_t)20 << 20));     // 8 KB  [m][d]
    u16* wqh = (u16*)(wsb + ((size_t)21 << 20));     // 2 MB
    u16* wkh = (u16*)(wsb + ((size_t)23 << 20));     // 0.5 MB
    u16* wvh = (u16*)(wsb + ((size_t)23 << 20) + ((size_t)512 << 10));  // 0.5 MB
    u16* woh = (u16*)(wsb + ((size_t)24 << 20));     // 2 MB
    // key/value bf16 live in d_out (16 MB), overwritten by final O-GEMM
    u16* Ki  = (u16*)d_out;                          // 8 MB
    u16* Vi  = Ki + (size_t)BB * TT * EE;            // 8 MB

    const int M = BB * TT;  // 4096
    // unit counts (8 elems each)
    const int nQ = M * EE / 8, nW = EE * EE / 8, nS = KVD * EE / 8;
    const int totalU = 3 * nQ + 2 * nW + 2 * nS;     // 1,900,544

    cast_all<<<(totalU + 255) / 256, 256, 0, stream>>>(
        query, Qi, nQ, key, Ki, nQ, value, Vi, nQ,
        wq, wqh, nW, wo, woh, nW, wk, wkh, nS, wv, wvh, nS);
    cast_posT<<<16, 256, 0, stream>>>(pos_emb, PT);

    gemm_bf16<128, 128><<<dim3(EE / 128, M / 128), 256, 0, stream>>>(
        Qi, wqh, bq, nullptr, Qh, M, EE, EE);
    kv_gemm<<<dim3(KVD / 64, 2 * M / 64), 256, 0, stream>>>(
        Ki, Vi, wkh, wvh, bk, bv, Kh, VhT);

    attn_mfma<<<BB * NH * (TT / 16), 256, 0, stream>>>(Qh, Kh, VhT, PT, AOh);

    gemm_bf16<128, 128><<<dim3(EE / 128, M / 128), 256, 0, stream>>>(
        AOh, woh, bo, out, nullptr, M, EE, EE);
}

// Round 6
// 323.763 us; speedup vs baseline: 5.3213x; 1.0621x over previous
//
#include <hip/hip_runtime.h>
#include <hip/hip_bf16.h>
#include <stdint.h>

typedef unsigned short u16;
typedef __attribute__((ext_vector_type(8))) short short8;
typedef __attribute__((ext_vector_type(4))) float f32x4;

#define BB 4
#define TT 1024
#define EE 1024
#define NH 16
#define NKV 4
#define HD 64
#define KVD 256
#define SR 1028   // sims row stride in floats (4112 B -> natural 4-bank/row stagger)

__device__ inline u16 f2bf(float f) {
    uint32_t u = __float_as_uint(f);
    uint32_t r = u + 0x7fffu + ((u >> 16) & 1u);
    return (u16)(r >> 16);
}

__device__ inline f32x4 mfma16(short8 a, short8 b, f32x4 c) {
    return __builtin_amdgcn_mfma_f32_16x16x32_bf16(a, b, c, 0, 0, 0);
}

// f32 sims region: self-inverse XOR of float-index bits 2-4 by col bits 5-7.
__device__ inline int simsIdx(int row, int col) {
    return row * SR + (col ^ (((col >> 5) & 7) << 2));
}

__device__ inline void gload16(const u16* g, u16* l) {
    __builtin_amdgcn_global_load_lds((const __attribute__((address_space(1))) void*)g,
                                     (__attribute__((address_space(3))) void*)l, 16, 0, 0);
}

__device__ inline void cast8(const float* s, u16* d) {
    const f32x4* p = (const f32x4*)s;
    f32x4 x = p[0], y = p[1];
    short8 v = (short8){(short)f2bf(x[0]), (short)f2bf(x[1]), (short)f2bf(x[2]), (short)f2bf(x[3]),
                        (short)f2bf(y[0]), (short)f2bf(y[1]), (short)f2bf(y[2]), (short)f2bf(y[3])};
    *(short8*)d = v;
}

// ---------------- fused f32->bf16 cast of all 7 tensors (counts in 8-elem units)
__global__ __launch_bounds__(256) void cast_all(
    const float* s0, u16* d0, int n0, const float* s1, u16* d1, int n1,
    const float* s2, u16* d2, int n2, const float* s3, u16* d3, int n3,
    const float* s4, u16* d4, int n4, const float* s5, u16* d5, int n5,
    const float* s6, u16* d6, int n6)
{
    int u = blockIdx.x * 256 + threadIdx.x;
    const float* s; u16* d; int off = u;
    if      (off < n0)              { s = s0; d = d0; }
    else if ((off -= n0) < n1)      { s = s1; d = d1; }
    else if ((off -= n1) < n2)      { s = s2; d = d2; }
    else if ((off -= n2) < n3)      { s = s3; d = d3; }
    else if ((off -= n3) < n4)      { s = s4; d = d4; }
    else if ((off -= n4) < n5)      { s = s5; d = d5; }
    else if ((off -= n5) < n6)      { s = s6; d = d6; }
    else return;
    cast8(s + (size_t)off * 8, d + (size_t)off * 8);
}

// ---------------- pos_emb [d][m] f32 -> PT [m][d] bf16
__global__ __launch_bounds__(256) void cast_posT(const float* __restrict__ pe, u16* __restrict__ PT) {
    int t = blockIdx.x * 256 + threadIdx.x;  // 0..4095
    PT[t] = f2bf(pe[(t & 63) * 64 + (t >> 6)]);
}

// ---------------- GEMM core: C += A[bm:,k] * W[bn:,k]^T, both bf16 [rows][K].
// Both panels via global_load_lds (linear LDS dest + inverse-swizzled source col).
template<int BM, int BN>
__device__ inline void gemm_core(const u16* __restrict__ A, const u16* __restrict__ W,
                                 int K, int bm, int bn, u16* As, u16* Bs,
                                 f32x4 (&acc)[BM / 32][BN / 32])
{
    const int t = threadIdx.x, l = t & 63, w = t >> 6;
    const int wr = w >> 1, wc = w & 1, lc = l & 15, lg = l >> 4;
    const int lr8 = l >> 3;
    const int c8s = (l & 7) ^ lr8;          // pre-swizzled source col8
    constexpr int FI = BM / 32, FJ = BN / 32;
    constexpr int NCA = BM / 8, NCW = BN / 8;

    for (int k0 = 0; k0 < K; k0 += 64) {
        #pragma unroll
        for (int r = 0; r < NCA / 4; ++r) {
            int chunk = w * (NCA / 4) + r;
            gload16(&A[(size_t)(bm + chunk * 8 + lr8) * K + k0 + c8s * 8], &As[chunk * 512]);
        }
        #pragma unroll
        for (int r = 0; r < NCW / 4; ++r) {
            int chunk = w * (NCW / 4) + r;
            gload16(&W[(size_t)(bn + chunk * 8 + lr8) * K + k0 + c8s * 8], &Bs[chunk * 512]);
        }
        __syncthreads();
        #pragma unroll
        for (int ks = 0; ks < 2; ++ks) {
            short8 af[FI], bfr[FJ];
            #pragma unroll
            for (int fi = 0; fi < FI; ++fi) {
                int row = wr * (BM / 2) + fi * 16 + lc;
                af[fi] = *(const short8*)((const char*)As +
                           ((row * 128 + (ks * 32 + lg * 8) * 2) ^ ((row & 7) << 4)));
            }
            #pragma unroll
            for (int fj = 0; fj < FJ; ++fj) {
                int row = wc * (BN / 2) + fj * 16 + lc;
                bfr[fj] = *(const short8*)((const char*)Bs +
                            ((row * 128 + (ks * 32 + lg * 8) * 2) ^ ((row & 7) << 4)));
            }
            #pragma unroll
            for (int fi = 0; fi < FI; ++fi)
                #pragma unroll
                for (int fj = 0; fj < FJ; ++fj)
                    acc[fi][fj] = mfma16(af[fi], bfr[fj], acc[fi][fj]);
        }
        __syncthreads();
    }
}

// ---------------- generic GEMM: writes f32 (Cf) or bf16 (Ch)
template<int BM, int BN>
__global__ __launch_bounds__(256) void gemm_bf16(const u16* __restrict__ A,
                                                 const u16* __restrict__ W,
                                                 const float* __restrict__ bias,
                                                 float* __restrict__ Cf, u16* __restrict__ Ch,
                                                 int M, int N, int K)
{
    __shared__ u16 As[BM * 64], Bs[BN * 64];
    const int bm = blockIdx.y * BM, bn = blockIdx.x * BN;
    const int l = threadIdx.x & 63, w = threadIdx.x >> 6;
    const int wr = w >> 1, wc = w & 1, lc = l & 15, lg = l >> 4;
    constexpr int FI = BM / 32, FJ = BN / 32;

    f32x4 acc[FI][FJ];
    #pragma unroll
    for (int i = 0; i < FI; ++i)
        #pragma unroll
        for (int j = 0; j < FJ; ++j) acc[i][j] = (f32x4){0.f, 0.f, 0.f, 0.f};

    gemm_core<BM, BN>(A, W, K, bm, bn, As, Bs, acc);

    #pragma unroll
    for (int fj = 0; fj < FJ; ++fj) {
        int col = bn + wc * (BN / 2) + fj * 16 + lc;
        float bv = bias[col];
        #pragma unroll
        for (int fi = 0; fi < FI; ++fi)
            #pragma unroll
            for (int r = 0; r < 4; ++r) {
                int row = bm + wr * (BM / 2) + fi * 16 + lg * 4 + r;
                float v = acc[fi][fj][r] + bv;
                if (Cf) Cf[(size_t)row * N + col] = v;
                else    Ch[(size_t)row * N + col] = f2bf(v);
            }
    }
}

// ---------------- fused K+V projection (BM=BN=64). blockIdx.y<64 -> K, else V.
__global__ __launch_bounds__(256) void kv_gemm(const u16* __restrict__ Ki, const u16* __restrict__ Vi,
                                               const u16* __restrict__ Wk, const u16* __restrict__ Wv,
                                               const float* __restrict__ bk, const float* __restrict__ bv,
                                               u16* __restrict__ Kh, u16* __restrict__ VhT)
{
    __shared__ u16 As[64 * 64], Bs[64 * 64];
    const int by = blockIdx.y;
    const bool isV = by >= 64;
    const u16* A = isV ? Vi : Ki;
    const u16* W = isV ? Wv : Wk;
    const float* bias = isV ? bv : bk;
    const int bm = (isV ? by - 64 : by) * 64, bn = blockIdx.x * 64;
    const int l = threadIdx.x & 63, w = threadIdx.x >> 6;
    const int wr = w >> 1, wc = w & 1, lc = l & 15, lg = l >> 4;

    f32x4 acc[2][2];
    #pragma unroll
    for (int i = 0; i < 2; ++i)
        #pragma unroll
        for (int j = 0; j < 2; ++j) acc[i][j] = (f32x4){0.f, 0.f, 0.f, 0.f};

    gemm_core<64, 64>(A, W, EE, bm, bn, As, Bs, acc);

    #pragma unroll
    for (int fj = 0; fj < 2; ++fj) {
        int col = bn + wc * 32 + fj * 16 + lc;
        float bvv = bias[col];
        #pragma unroll
        for (int fi = 0; fi < 2; ++fi)
            #pragma unroll
            for (int r = 0; r < 4; ++r) {
                int row = bm + wr * 32 + fi * 16 + lg * 4 + r;
                float v = acc[fi][fj][r] + bvv;
                if (!isV) {
                    Kh[(size_t)row * KVD + col] = f2bf(v);
                } else {  // V transposed per head: [(b,kv,d)][t]
                    int bb = row >> 10, tt = row & 1023, kv = col >> 6, d = col & 63;
                    VhT[(size_t)((bb * NKV + kv) * HD + d) * TT + tt] = f2bf(v);
                }
            }
    }
}

// ---------------- fused CoPE attention. Block = (b, head, 16 q-rows), 8 waves.
// Occupancy fix: 512 threads -> 2 rows/wave scan, 4 waves/SIMD resident.
__global__ __launch_bounds__(512) void attn_mfma(const u16* __restrict__ Qh,
                                                 const u16* __restrict__ Kh,
                                                 const u16* __restrict__ VhT,
                                                 const u16* __restrict__ PT,
                                                 u16* __restrict__ AOh)
{
    __shared__ float sims[16 * SR];   // 65,792 B (f32 S; row-prefix reused as bf16 P)
    __shared__ float li[1092];        // 4,368 B: li[i*65+m] in scan; PV partial buf after
    __shared__ float rinv[16];

    const int blk = blockIdx.x;
    const int it = blk & 63, bh = blk >> 6;
    const int head = bh & 15, b = bh >> 4, kvh = head & 3;
    const int i0 = it * 16;
    const int t = threadIdx.x, l = t & 63, w = t >> 6;   // w in 0..7
    const int lc = l & 15, lg = l >> 4;

    // Q A-fragments (rows i0..i0+15, k=d 0..63) — every wave
    short8 qf[2];
    #pragma unroll
    for (int kk = 0; kk < 2; ++kk)
        qf[kk] = *(const short8*)(Qh + (size_t)(b * TT + i0 + lc) * EE + head * HD + kk * 32 + lg * 8);

    // li[i][m] = q_i . pos_emb[:,m]  (waves 0-3 cover m-subtiles)
    if (w < 4) {
        f32x4 a = {0.f, 0.f, 0.f, 0.f};
        #pragma unroll
        for (int kk = 0; kk < 2; ++kk) {
            short8 bfr = *(const short8*)(PT + (w * 16 + lc) * 64 + kk * 32 + lg * 8);
            a = mfma16(qf[kk], bfr, a);
        }
        #pragma unroll
        for (int r = 0; r < 4; ++r) li[(lg * 4 + r) * 65 + w * 16 + lc] = a[r];
    }
    if (t < 16) li[t * 65 + 64] = 0.f;   // pad for lo+1 gather

    // ---- QK^T: 64 col-chunks of 16; wave w owns chunks w*8 .. w*8+7
    const u16* kb = Kh + (size_t)(b * TT) * KVD + kvh * HD;
    #pragma unroll 2
    for (int cc = 0; cc < 8; ++cc) {
        const int j0 = (w * 8 + cc) * 16;
        const u16* kr = kb + (size_t)(j0 + lc) * KVD;
        short8 k0v = *(const short8*)(kr + lg * 8);
        short8 k1v = *(const short8*)(kr + 32 + lg * 8);
        f32x4 a = {0.f, 0.f, 0.f, 0.f};
        a = mfma16(qf[0], k0v, a);
        a = mfma16(qf[1], k1v, a);
        #pragma unroll
        for (int r = 0; r < 4; ++r)
            sims[simsIdx(lg * 4 + r, j0 + lc)] = a[r] * 0.125f;
    }
    __syncthreads();

    // ---- CoPE scan + softmax; 2 rows per wave; pack unnormalized P (bf16) in place
    #pragma unroll 1
    for (int rr = 0; rr < 2; ++rr) {
        const int i = w * 2 + rr;
        float sv[16];
        #pragma unroll
        for (int q = 0; q < 4; ++q) {
            f32x4 x = *(const f32x4*)&sims[simsIdx(i, l * 16 + q * 4)];
            sv[q * 4 + 0] = x[0]; sv[q * 4 + 1] = x[1];
            sv[q * 4 + 2] = x[2]; sv[q * 4 + 3] = x[3];
        }
        // local exclusive prefix of gates + single cross-lane scan
        float lexcl[16];
        float ex = 0.f;
        #pragma unroll
        for (int k = 0; k < 16; ++k) {
            lexcl[k] = ex;
            ex += __fdividef(1.f, 1.f + __expf(-sv[k]));
        }
        float v = ex;
        #pragma unroll
        for (int off = 1; off < 64; off <<= 1) {
            float n = __shfl_up(v, off, 64);
            if (l >= off) v += n;
        }
        const float total = __shfl(v, 63, 64);
        const float lexb = v - ex;
        const float* lp = &li[i * 65];
        float rmax = -1e30f;
        #pragma unroll
        for (int k = 0; k < 16; ++k) {
            float pos = total - (lexb + lexcl[k]);
            pos = fminf(fmaxf(pos, 0.f), 63.f);
            float pf = floorf(pos);
            float wt = pos - pf;
            int lo = (int)pf;
            float l0 = lp[lo], l1 = lp[lo + 1];
            sv[k] += l0 + wt * (l1 - l0);
            rmax = fmaxf(rmax, sv[k]);
        }
        #pragma unroll
        for (int off = 32; off; off >>= 1) rmax = fmaxf(rmax, __shfl_xor(rmax, off, 64));
        float rsum = 0.f;
        #pragma unroll
        for (int k = 0; k < 16; ++k) { sv[k] = __expf(sv[k] - rmax); rsum += sv[k]; }
        #pragma unroll
        for (int off = 32; off; off >>= 1) rsum += __shfl_xor(rsum, off, 64);
        if (l == 0) rinv[i] = __fdividef(1.f, rsum);
        // pack unnormalized P into row-prefix (bytes [0,2048) of the row)
        u16* sp = (u16*)sims + (size_t)i * (SR * 2) + l * 16;
        short8 p0 = (short8){(short)f2bf(sv[0]), (short)f2bf(sv[1]), (short)f2bf(sv[2]), (short)f2bf(sv[3]),
                             (short)f2bf(sv[4]), (short)f2bf(sv[5]), (short)f2bf(sv[6]), (short)f2bf(sv[7])};
        short8 p1 = (short8){(short)f2bf(sv[8]), (short)f2bf(sv[9]), (short)f2bf(sv[10]), (short)f2bf(sv[11]),
                             (short)f2bf(sv[12]), (short)f2bf(sv[13]), (short)f2bf(sv[14]), (short)f2bf(sv[15])};
        *(short8*)sp = p0;
        *(short8*)(sp + 8) = p1;
    }
    __syncthreads();

    // ---- PV: d-subtile (w&3); j-half (w>>2). Partials reduced via li-LDS.
    const int dsub = w & 3, jh = w >> 2;
    const u16* sp = (const u16*)sims;
    const u16* vr = VhT + ((size_t)((b * NKV + kvh) * HD) + dsub * 16 + lc) * TT;
    f32x4 oacc = {0.f, 0.f, 0.f, 0.f};
    #pragma unroll 2
    for (int jj = 0; jj < 8; ++jj) {
        int jt = jh * 8 + jj;
        #pragma unroll
        for (int kt = 0; kt < 2; ++kt) {
            int col = jt * 64 + kt * 32 + lg * 8;
            short8 pa = *(const short8*)(sp + (size_t)lc * (SR * 2) + col);
            short8 vf = *(const short8*)(vr + col);
            oacc = mfma16(pa, vf, oacc);
        }
    }
    if (w >= 4) {  // stash partial: pbuf[dsub][row][col], stride 17
        #pragma unroll
        for (int r = 0; r < 4; ++r)
            li[dsub * 272 + (lg * 4 + r) * 17 + lc] = oacc[r];
    }
    __syncthreads();
    if (w < 4) {
        #pragma unroll
        for (int r = 0; r < 4; ++r) {
            float o = (oacc[r] + li[dsub * 272 + (lg * 4 + r) * 17 + lc]) * rinv[lg * 4 + r];
            AOh[(size_t)(b * TT + i0 + lg * 4 + r) * EE + head * HD + dsub * 16 + lc] = f2bf(o);
        }
    }
}

extern "C" void kernel_launch(void* const* d_in, const int* in_sizes, int n_in,
                              void* d_out, int out_size, void* d_ws, size_t ws_size,
                              hipStream_t stream)
{
    const float* query   = (const float*)d_in[0];
    const float* key     = (const float*)d_in[1];
    const float* value   = (const float*)d_in[2];
    const float* wq      = (const float*)d_in[3];
    const float* bq      = (const float*)d_in[4];
    const float* wk      = (const float*)d_in[5];
    const float* bk      = (const float*)d_in[6];
    const float* wv      = (const float*)d_in[7];
    const float* bv      = (const float*)d_in[8];
    const float* wo      = (const float*)d_in[9];
    const float* bo      = (const float*)d_in[10];
    const float* pos_emb = (const float*)d_in[11];
    float* out = (float*)d_out;

    char* wsb = (char*)d_ws;
    u16* Qh  = (u16*)(wsb);                          // 8 MB  [token][1024]
    u16* Kh  = (u16*)(wsb + ((size_t)8  << 20));     // 2 MB  [token][256]
    u16* VhT = (u16*)(wsb + ((size_t)10 << 20));     // 2 MB  [(b,kv,d)][t]
    u16* Qi  = (u16*)(wsb + ((size_t)12 << 20));     // 8 MB  query bf16 (dead after Q-GEMM)
    u16* AOh = Qi;                                   // 8 MB  attn out (reuses Qi)
    u16* PT  = (u16*)(wsb + ((size_t)20 << 20));     // 8 KB  [m][d]
    u16* wqh = (u16*)(wsb + ((size_t)21 << 20));     // 2 MB
    u16* wkh = (u16*)(wsb + ((size_t)23 << 20));     // 0.5 MB
    u16* wvh = (u16*)(wsb + ((size_t)23 << 20) + ((size_t)512 << 10));  // 0.5 MB
    u16* woh = (u16*)(wsb + ((size_t)24 << 20));     // 2 MB
    // key/value bf16 live in d_out (16 MB), overwritten by final O-GEMM
    u16* Ki  = (u16*)d_out;                          // 8 MB
    u16* Vi  = Ki + (size_t)BB * TT * EE;            // 8 MB

    const int M = BB * TT;  // 4096
    // unit counts (8 elems each)
    const int nQ = M * EE / 8, nW = EE * EE / 8, nS = KVD * EE / 8;
    const int totalU = 3 * nQ + 2 * nW + 2 * nS;     // 1,900,544

    cast_all<<<(totalU + 255) / 256, 256, 0, stream>>>(
        query, Qi, nQ, key, Ki, nQ, value, Vi, nQ,
        wq, wqh, nW, wo, woh, nW, wk, wkh, nS, wv, wvh, nS);
    cast_posT<<<16, 256, 0, stream>>>(pos_emb, PT);

    gemm_bf16<128, 64><<<dim3(EE / 64, M / 128), 256, 0, stream>>>(
        Qi, wqh, bq, nullptr, Qh, M, EE, EE);
    kv_gemm<<<dim3(KVD / 64, 2 * M / 64), 256, 0, stream>>>(
        Ki, Vi, wkh, wvh, bk, bv, Kh, VhT);

    attn_mfma<<<BB * NH * (TT / 16), 512, 0, stream>>>(Qh, Kh, VhT, PT, AOh);

    gemm_bf16<128, 64><<<dim3(EE / 64, M / 128), 256, 0, stream>>>(
        AOh, woh, bo, out, nullptr, M, EE, EE);
}

// Round 10
// 289.899 us; speedup vs baseline: 5.9429x; 1.1168x over previous
//
#include <hip/hip_runtime.h>
#include <hip/hip_bf16.h>
#include <stdint.h>

typedef unsigned short u16;
typedef unsigned int u32;
typedef __attribute__((ext_vector_type(4))) short s16x4;
typedef __attribute__((ext_vector_type(8))) short short8;
typedef __attribute__((ext_vector_type(4))) float f32x4;

#define BB 4
#define TT 1024
#define EE 1024
#define NH 16
#define NKV 4
#define HD 64
#define KVD 256
#define WSTRIDE 1296   // per-wave LDS floats: li 16*65=1040 + pbuf 256 (1024 B)

__device__ inline u16 f2bf(float f) {
    u32 u = __float_as_uint(f);
    u32 r = u + 0x7fffu + ((u >> 16) & 1u);
    return (u16)(r >> 16);
}

__device__ inline f32x4 mfma16(short8 a, short8 b, f32x4 c) {
    return __builtin_amdgcn_mfma_f32_16x16x32_bf16(a, b, c, 0, 0, 0);
}

__device__ inline void gload16(const u16* g, u16* l) {
    __builtin_amdgcn_global_load_lds((const __attribute__((address_space(1))) void*)g,
                                     (__attribute__((address_space(3))) void*)l, 16, 0, 0);
}

__device__ inline void cast8(const float* s, u16* d) {
    const f32x4* p = (const f32x4*)s;
    f32x4 x = p[0], y = p[1];
    short8 v = (short8){(short)f2bf(x[0]), (short)f2bf(x[1]), (short)f2bf(x[2]), (short)f2bf(x[3]),
                        (short)f2bf(y[0]), (short)f2bf(y[1]), (short)f2bf(y[2]), (short)f2bf(y[3])};
    *(short8*)d = v;
}

// ---------------- fused f32->bf16 cast of all 7 tensors (counts in 8-elem units)
__global__ __launch_bounds__(256) void cast_all(
    const float* s0, u16* d0, int n0, const float* s1, u16* d1, int n1,
    const float* s2, u16* d2, int n2, const float* s3, u16* d3, int n3,
    const float* s4, u16* d4, int n4, const float* s5, u16* d5, int n5,
    const float* s6, u16* d6, int n6)
{
    int u = blockIdx.x * 256 + threadIdx.x;
    const float* s; u16* d; int off = u;
    if      (off < n0)              { s = s0; d = d0; }
    else if ((off -= n0) < n1)      { s = s1; d = d1; }
    else if ((off -= n1) < n2)      { s = s2; d = d2; }
    else if ((off -= n2) < n3)      { s = s3; d = d3; }
    else if ((off -= n3) < n4)      { s = s4; d = d4; }
    else if ((off -= n4) < n5)      { s = s5; d = d5; }
    else if ((off -= n5) < n6)      { s = s6; d = d6; }
    else return;
    cast8(s + (size_t)off * 8, d + (size_t)off * 8);
}

// ---------------- pos_emb [d][m] f32 -> PT [m][d] bf16
__global__ __launch_bounds__(256) void cast_posT(const float* __restrict__ pe, u16* __restrict__ PT) {
    int t = blockIdx.x * 256 + threadIdx.x;  // 0..4095
    PT[t] = f2bf(pe[(t & 63) * 64 + (t >> 6)]);
}

// ---------------- GEMM core: C += A[bm:,k] * W[bn:,k]^T, both bf16 [rows][K].
template<int BM, int BN>
__device__ inline void gemm_core(const u16* __restrict__ A, const u16* __restrict__ W,
                                 int K, int bm, int bn, u16* As, u16* Bs,
                                 f32x4 (&acc)[BM / 32][BN / 32])
{
    const int t = threadIdx.x, l = t & 63, w = t >> 6;
    const int wr = w >> 1, wc = w & 1, lc = l & 15, lg = l >> 4;
    const int lr8 = l >> 3;
    const int c8s = (l & 7) ^ lr8;          // pre-swizzled source col8
    constexpr int FI = BM / 32, FJ = BN / 32;
    constexpr int NCA = BM / 8, NCW = BN / 8;

    for (int k0 = 0; k0 < K; k0 += 64) {
        #pragma unroll
        for (int r = 0; r < NCA / 4; ++r) {
            int chunk = w * (NCA / 4) + r;
            gload16(&A[(size_t)(bm + chunk * 8 + lr8) * K + k0 + c8s * 8], &As[chunk * 512]);
        }
        #pragma unroll
        for (int r = 0; r < NCW / 4; ++r) {
            int chunk = w * (NCW / 4) + r;
            gload16(&W[(size_t)(bn + chunk * 8 + lr8) * K + k0 + c8s * 8], &Bs[chunk * 512]);
        }
        __syncthreads();
        #pragma unroll
        for (int ks = 0; ks < 2; ++ks) {
            short8 af[FI], bfr[FJ];
            #pragma unroll
            for (int fi = 0; fi < FI; ++fi) {
                int row = wr * (BM / 2) + fi * 16 + lc;
                af[fi] = *(const short8*)((const char*)As +
                           ((row * 128 + (ks * 32 + lg * 8) * 2) ^ ((row & 7) << 4)));
            }
            #pragma unroll
            for (int fj = 0; fj < FJ; ++fj) {
                int row = wc * (BN / 2) + fj * 16 + lc;
                bfr[fj] = *(const short8*)((const char*)Bs +
                            ((row * 128 + (ks * 32 + lg * 8) * 2) ^ ((row & 7) << 4)));
            }
            #pragma unroll
            for (int fi = 0; fi < FI; ++fi)
                #pragma unroll
                for (int fj = 0; fj < FJ; ++fj)
                    acc[fi][fj] = mfma16(af[fi], bfr[fj], acc[fi][fj]);
        }
        __syncthreads();
    }
}

// ---------------- generic GEMM: writes f32 (Cf) or bf16 (Ch)
template<int BM, int BN>
__global__ __launch_bounds__(256) void gemm_bf16(const u16* __restrict__ A,
                                                 const u16* __restrict__ W,
                                                 const float* __restrict__ bias,
                                                 float* __restrict__ Cf, u16* __restrict__ Ch,
                                                 int M, int N, int K)
{
    __shared__ u16 As[BM * 64], Bs[BN * 64];
    const int bm = blockIdx.y * BM, bn = blockIdx.x * BN;
    const int l = threadIdx.x & 63, w = threadIdx.x >> 6;
    const int wr = w >> 1, wc = w & 1, lc = l & 15, lg = l >> 4;
    constexpr int FI = BM / 32, FJ = BN / 32;

    f32x4 acc[FI][FJ];
    #pragma unroll
    for (int i = 0; i < FI; ++i)
        #pragma unroll
        for (int j = 0; j < FJ; ++j) acc[i][j] = (f32x4){0.f, 0.f, 0.f, 0.f};

    gemm_core<BM, BN>(A, W, K, bm, bn, As, Bs, acc);

    #pragma unroll
    for (int fj = 0; fj < FJ; ++fj) {
        int col = bn + wc * (BN / 2) + fj * 16 + lc;
        float bv = bias[col];
        #pragma unroll
        for (int fi = 0; fi < FI; ++fi)
            #pragma unroll
            for (int r = 0; r < 4; ++r) {
                int row = bm + wr * (BM / 2) + fi * 16 + lg * 4 + r;
                float v = acc[fi][fj][r] + bv;
                if (Cf) Cf[(size_t)row * N + col] = v;
                else    Ch[(size_t)row * N + col] = f2bf(v);
            }
    }
}

// ---------------- fused K+V projection (BM=BN=64). blockIdx.y<64 -> K, else V.
__global__ __launch_bounds__(256) void kv_gemm(const u16* __restrict__ Ki, const u16* __restrict__ Vi,
                                               const u16* __restrict__ Wk, const u16* __restrict__ Wv,
                                               const float* __restrict__ bk, const float* __restrict__ bv,
                                               u16* __restrict__ Kh, u16* __restrict__ VhT)
{
    __shared__ u16 As[64 * 64], Bs[64 * 64];
    const int by = blockIdx.y;
    const bool isV = by >= 64;
    const u16* A = isV ? Vi : Ki;
    const u16* W = isV ? Wv : Wk;
    const float* bias = isV ? bv : bk;
    const int bm = (isV ? by - 64 : by) * 64, bn = blockIdx.x * 64;
    const int l = threadIdx.x & 63, w = threadIdx.x >> 6;
    const int wr = w >> 1, wc = w & 1, lc = l & 15, lg = l >> 4;

    f32x4 acc[2][2];
    #pragma unroll
    for (int i = 0; i < 2; ++i)
        #pragma unroll
        for (int j = 0; j < 2; ++j) acc[i][j] = (f32x4){0.f, 0.f, 0.f, 0.f};

    gemm_core<64, 64>(A, W, EE, bm, bn, As, Bs, acc);

    #pragma unroll
    for (int fj = 0; fj < 2; ++fj) {
        int col = bn + wc * 32 + fj * 16 + lc;
        float bvv = bias[col];
        #pragma unroll
        for (int fi = 0; fi < 2; ++fi)
            #pragma unroll
            for (int r = 0; r < 4; ++r) {
                int row = bm + wr * 32 + fi * 16 + lg * 4 + r;
                float v = acc[fi][fj][r] + bvv;
                if (!isV) {
                    Kh[(size_t)row * KVD + col] = f2bf(v);
                } else {  // V transposed per head: [(b,kv,d)][t]
                    int bb = row >> 10, tt = row & 1023, kv = col >> 6, d = col & 63;
                    VhT[(size_t)((bb * NKV + kv) * HD + d) * TT + tt] = f2bf(v);
                }
            }
    }
}

// ---------------- flash-CoPE attention: one WAVE per (b, head, 16 q-rows).
// j-pairs HIGH->LOW; online suffix-carry; exact fast path once carry>=63.
// Swapped QK^T keeps S^T lane-local; online softmax; PV via per-wave 1 KB
// LDS repack (16 q x 32 j bf16).
__global__ __launch_bounds__(256) void attn_flash(const u16* __restrict__ Qh,
                                                  const u16* __restrict__ Kh,
                                                  const u16* __restrict__ VhT,
                                                  const u16* __restrict__ PT,
                                                  u16* __restrict__ AOh)
{
    __shared__ float lds_all[4 * WSTRIDE];   // per wave: li 1040 f32 + pbuf 1024 B
    const int t = threadIdx.x, l = t & 63, w = t >> 6;
    float* li = lds_all + w * WSTRIDE;
    u16* pbuf = (u16*)(li + 1040);

    const int bid = blockIdx.x;
    const int wgs = (bid & 7) * 128 + (bid >> 3);   // XCD-contiguous remap (1024 wgs)
    const int gw = wgs * 4 + w;                     // q-tile id 0..4095
    const int it = gw & 63, bh = gw >> 6;
    const int head = bh & 15, b = bh >> 4, kvh = head & 3;
    const int i0 = it * 16;
    const int lc = l & 15, lg = l >> 4;

    // Q B-fragments (col=q=i0+lc, k=d)
    short8 qf[2];
    #pragma unroll
    for (int kk = 0; kk < 2; ++kk)
        qf[kk] = *(const short8*)(Qh + (size_t)(b * TT + i0 + lc) * EE + head * HD + kk * 32 + lg * 8);

    // li^T[m][q] via swapped mfma (A = PT rows m); store li[q][m]
    #pragma unroll
    for (int ms = 0; ms < 4; ++ms) {
        f32x4 a = {0.f, 0.f, 0.f, 0.f};
        #pragma unroll
        for (int kk = 0; kk < 2; ++kk)
            a = mfma16(*(const short8*)(PT + (ms * 16 + lc) * 64 + kk * 32 + lg * 8), qf[kk], a);
        #pragma unroll
        for (int r = 0; r < 4; ++r)
            li[lc * 65 + ms * 16 + lg * 4 + r] = a[r];
    }
    li[lc * 65 + 64] = 0.f;              // pad for lo+1 gather (same-value lane race ok)
    asm volatile("" ::: "memory");
    const float li63 = li[lc * 65 + 63];

    const u16* kb = Kh + (size_t)(b * TT) * KVD + kvh * HD;
    const u16* vb = VhT + (size_t)((b * NKV + kvh) * HD) * TT;

    float mrun = -1e30f, rsum = 0.f, carry = 0.f;
    f32x4 oacc[4];
    #pragma unroll
    for (int d4 = 0; d4 < 4; ++d4) oacc[d4] = (f32x4){0.f, 0.f, 0.f, 0.f};

    // K A-frags for pair 31 (prefetch pipeline)
    short8 kf0, kf1, kf2, kf3;
    {
        const u16* krL = kb + (size_t)(31 * 32 + lc) * KVD;
        const u16* krH = kb + (size_t)(31 * 32 + 16 + lc) * KVD;
        kf0 = *(const short8*)(krL + lg * 8);
        kf1 = *(const short8*)(krL + 32 + lg * 8);
        kf2 = *(const short8*)(krH + lg * 8);
        kf3 = *(const short8*)(krH + 32 + lg * 8);
    }

    for (int p = 31; p >= 0; --p) {
        const int t0 = p * 32;
        short8 kn0 = kf0, kn1 = kf1, kn2 = kf2, kn3 = kf3;
        if (p > 0) {   // issue next pair's K loads early
            const u16* krL = kb + (size_t)(t0 - 32 + lc) * KVD;
            const u16* krH = kb + (size_t)(t0 - 32 + 16 + lc) * KVD;
            kn0 = *(const short8*)(krL + lg * 8);
            kn1 = *(const short8*)(krL + 32 + lg * 8);
            kn2 = *(const short8*)(krH + lg * 8);
            kn3 = *(const short8*)(krH + 32 + lg * 8);
        }
        // S^T: lane holds j = t0 + 16*tileHL + lg*4+r for q = i0+lc
        f32x4 sL4 = {0.f, 0.f, 0.f, 0.f}, sH4 = {0.f, 0.f, 0.f, 0.f};
        sL4 = mfma16(kf0, qf[0], sL4); sL4 = mfma16(kf1, qf[1], sL4);
        sH4 = mfma16(kf2, qf[0], sH4); sH4 = mfma16(kf3, qf[1], sH4);

        float aL[4], aH[4];
        const bool fast = __all(carry >= 63.0f);
        if (fast) {
            #pragma unroll
            for (int r = 0; r < 4; ++r) {
                aL[r] = sL4[r] * 0.125f + li63;
                aH[r] = sH4[r] * 0.125f + li63;
            }
        } else {
            float sL[4], sH[4], gL[4], gH[4];
            #pragma unroll
            for (int r = 0; r < 4; ++r) {
                sL[r] = sL4[r] * 0.125f; sH[r] = sH4[r] * 0.125f;
                gL[r] = __fdividef(1.f, 1.f + __expf(-sL[r]));
                gH[r] = __fdividef(1.f, 1.f + __expf(-sH[r]));
            }
            // HI tile first (higher j): in-lane suffix + lg-group exchange
            float oh3 = gH[3], oh2 = gH[2] + oh3, oh1 = gH[1] + oh2, oh0 = gH[0] + oh1;
            float tH = oh0;
            float aX = __shfl_xor(tH, 16), bX = __shfl_xor(tH, 32), cX = __shfl_xor(aX, 32);
            float hiH = (lg == 0) ? aX + bX + cX : (lg == 1) ? bX + cX : (lg == 2) ? aX : 0.f;
            float totH = tH + aX + bX + cX;
            float baseH = carry + hiH;
            float carryM = carry + totH;
            float ol3 = gL[3], ol2 = gL[2] + ol3, ol1 = gL[1] + ol2, ol0 = gL[0] + ol1;
            float tL = ol0;
            float aY = __shfl_xor(tL, 16), bY = __shfl_xor(tL, 32), cY = __shfl_xor(aY, 32);
            float hiL = (lg == 0) ? aY + bY + cY : (lg == 1) ? bY + cY : (lg == 2) ? aY : 0.f;
            float totL = tL + aY + bY + cY;
            float baseL = carryM + hiL;
            carry = carryM + totL;
            const float* lp = &li[lc * 65];
            float osf[4] = {oh0, oh1, oh2, oh3};
            float osl[4] = {ol0, ol1, ol2, ol3};
            #pragma unroll
            for (int r = 0; r < 4; ++r) {
                float pos = fminf(baseH + osf[r], 63.f);
                float pf = floorf(pos), wt = pos - pf;
                int lo = (int)pf;
                float l0 = lp[lo], l1 = lp[lo + 1];
                aH[r] = sH[r] + l0 + wt * (l1 - l0);
            }
            #pragma unroll
            for (int r = 0; r < 4; ++r) {
                float pos = fminf(baseL + osl[r], 63.f);
                float pf = floorf(pos), wt = pos - pf;
                int lo = (int)pf;
                float l0 = lp[lo], l1 = lp[lo + 1];
                aL[r] = sL[r] + l0 + wt * (l1 - l0);
            }
        }
        // online softmax (per q=lc; lg groups merged via shfl_xor 16/32)
        float mt = fmaxf(fmaxf(fmaxf(aL[0], aL[1]), fmaxf(aL[2], aL[3])),
                         fmaxf(fmaxf(aH[0], aH[1]), fmaxf(aH[2], aH[3])));
        mt = fmaxf(mt, __shfl_xor(mt, 16));
        mt = fmaxf(mt, __shfl_xor(mt, 32));
        float mnew = fmaxf(mrun, mt);
        float sc = __expf(mrun - mnew);
        float pL[4], pH[4];
        float ts = 0.f;
        #pragma unroll
        for (int r = 0; r < 4; ++r) {
            pL[r] = __expf(aL[r] - mnew); ts += pL[r];
            pH[r] = __expf(aH[r] - mnew); ts += pH[r];
        }
        ts += __shfl_xor(ts, 16);
        ts += __shfl_xor(ts, 32);
        rsum = rsum * sc + ts;
        if (__any(mt > mrun)) {
            #pragma unroll
            for (int d4 = 0; d4 < 4; ++d4) {
                oacc[d4][0] *= sc; oacc[d4][1] *= sc; oacc[d4][2] *= sc; oacc[d4][3] *= sc;
            }
        }
        mrun = mnew;
        // repack P^T -> B-operand via per-wave 1 KB LDS buffer [q=16][j=32] bf16.
        s16x4 w0 = (s16x4){(short)f2bf(pL[0]), (short)f2bf(pL[1]), (short)f2bf(pL[2]), (short)f2bf(pL[3])};
        s16x4 w1 = (s16x4){(short)f2bf(pH[0]), (short)f2bf(pH[1]), (short)f2bf(pH[2]), (short)f2bf(pH[3])};
        *(s16x4*)((char*)pbuf + lc * 64 + lg * 8)      = w0;
        *(s16x4*)((char*)pbuf + lc * 64 + 32 + lg * 8) = w1;
        asm volatile("" ::: "memory");
        short8 pfrag = *(const short8*)((const char*)pbuf + lc * 64 + lg * 16);
        asm volatile("" ::: "memory");
        // PV: O^T[d][q] += V^T-tile * P  (A = V^T rows d, k = j)
        #pragma unroll
        for (int d4 = 0; d4 < 4; ++d4)
            oacc[d4] = mfma16(*(const short8*)(vb + (size_t)(d4 * 16 + lc) * TT + t0 + lg * 8),
                              pfrag, oacc[d4]);
        kf0 = kn0; kf1 = kn1; kf2 = kn2; kf3 = kn3;
    }

    const float rinv = __fdividef(1.f, rsum);
    u16* ob = AOh + (size_t)(b * TT + i0 + lc) * EE + head * HD + lg * 4;
    #pragma unroll
    for (int d4 = 0; d4 < 4; ++d4) {
        s16x4 pk = (s16x4){(short)f2bf(oacc[d4][0] * rinv), (short)f2bf(oacc[d4][1] * rinv),
                           (short)f2bf(oacc[d4][2] * rinv), (short)f2bf(oacc[d4][3] * rinv)};
        *(s16x4*)(ob + d4 * 16) = pk;
    }
}

extern "C" void kernel_launch(void* const* d_in, const int* in_sizes, int n_in,
                              void* d_out, int out_size, void* d_ws, size_t ws_size,
                              hipStream_t stream)
{
    const float* query   = (const float*)d_in[0];
    const float* key     = (const float*)d_in[1];
    const float* value   = (const float*)d_in[2];
    const float* wq      = (const float*)d_in[3];
    const float* bq      = (const float*)d_in[4];
    const float* wk      = (const float*)d_in[5];
    const float* bk      = (const float*)d_in[6];
    const float* wv      = (const float*)d_in[7];
    const float* bv      = (const float*)d_in[8];
    const float* wo      = (const float*)d_in[9];
    const float* bo      = (const float*)d_in[10];
    const float* pos_emb = (const float*)d_in[11];
    float* out = (float*)d_out;

    char* wsb = (char*)d_ws;
    u16* Qh  = (u16*)(wsb);                          // 8 MB  [token][1024]
    u16* Kh  = (u16*)(wsb + ((size_t)8  << 20));     // 2 MB  [token][256]
    u16* VhT = (u16*)(wsb + ((size_t)10 << 20));     // 2 MB  [(b,kv,d)][t]
    u16* Qi  = (u16*)(wsb + ((size_t)12 << 20));     // 8 MB  query bf16 (dead after Q-GEMM)
    u16* AOh = Qi;                                   // 8 MB  attn out (reuses Qi)
    u16* PT  = (u16*)(wsb + ((size_t)20 << 20));     // 8 KB  [m][d]
    u16* wqh = (u16*)(wsb + ((size_t)21 << 20));     // 2 MB
    u16* wkh = (u16*)(wsb + ((size_t)23 << 20));     // 0.5 MB
    u16* wvh = (u16*)(wsb + ((size_t)23 << 20) + ((size_t)512 << 10));  // 0.5 MB
    u16* woh = (u16*)(wsb + ((size_t)24 << 20));     // 2 MB
    // key/value bf16 live in d_out (16 MB), overwritten by final O-GEMM
    u16* Ki  = (u16*)d_out;                          // 8 MB
    u16* Vi  = Ki + (size_t)BB * TT * EE;            // 8 MB

    const int M = BB * TT;  // 4096
    const int nQ = M * EE / 8, nW = EE * EE / 8, nS = KVD * EE / 8;
    const int totalU = 3 * nQ + 2 * nW + 2 * nS;

    cast_all<<<(totalU + 255) / 256, 256, 0, stream>>>(
        query, Qi, nQ, key, Ki, nQ, value, Vi, nQ,
        wq, wqh, nW, wo, woh, nW, wk, wkh, nS, wv, wvh, nS);
    cast_posT<<<16, 256, 0, stream>>>(pos_emb, PT);

    gemm_bf16<128, 64><<<dim3(EE / 64, M / 128), 256, 0, stream>>>(
        Qi, wqh, bq, nullptr, Qh, M, EE, EE);
    kv_gemm<<<dim3(KVD / 64, 2 * M / 64), 256, 0, stream>>>(
        Ki, Vi, wkh, wvh, bk, bv, Kh, VhT);

    attn_flash<<<BB * NH * (TT / 16) / 4, 256, 0, stream>>>(Qh, Kh, VhT, PT, AOh);

    gemm_bf16<128, 64><<<dim3(EE / 64, M / 128), 256, 0, stream>>>(
        AOh, woh, bo, out, nullptr, M, EE, EE);
}